// Round 1
// baseline (18993.323 us; speedup 1.0000x reference)
//
#include <hip/hip_runtime.h>

#define NNODES 50000
#define NEDGES 800000
#define HDIM 128
#define OUTDIM 64

// ---------------- degree / norm ----------------
__global__ void deg_kernel(const int* __restrict__ dst, float* __restrict__ deg) {
    int e = blockIdx.x * 256 + threadIdx.x;
    if (e < NEDGES) atomicAdd(&deg[dst[e]], 1.0f);
}

__global__ void norm_kernel(float* __restrict__ buf) {
    int n = blockIdx.x * 256 + threadIdx.x;
    if (n < NNODES) buf[n] = rsqrtf(1.0f + buf[n]);
}

// ---------------- matmul + norm-scale epilogue: y = (x @ W) * norm[row] ----
// K is always 128. OUTD in {128, 64}. block = (OUTD, 256/OUTD); each thread
// computes 4 rows x 1 col. Rows per block: 8 (OUTD=128) or 16 (OUTD=64);
// N=50000 divides both exactly.
template <int OUTD>
__global__ __launch_bounds__(256) void matmul_norm_kernel(
    const float* __restrict__ x, const float* __restrict__ W,
    const float* __restrict__ norm, float* __restrict__ y) {
    constexpr int TY = 256 / OUTD;
    constexpr int RPB = TY * 4;
    __shared__ float xs[RPB][128];
    const int tid = threadIdx.y * OUTD + threadIdx.x;
    const int row0 = blockIdx.x * RPB;
    for (int i = tid; i < RPB * 128; i += 256) {
        int r = i >> 7, k = i & 127;
        xs[r][k] = x[(size_t)(row0 + r) * 128 + k];
    }
    __syncthreads();
    const int col = threadIdx.x;
    const int rbase = threadIdx.y * 4;
    float acc[4] = {0.f, 0.f, 0.f, 0.f};
    for (int k = 0; k < 128; ++k) {
        float wk = W[k * OUTD + col];
#pragma unroll
        for (int r = 0; r < 4; ++r) acc[r] += xs[rbase + r][k] * wk;
    }
#pragma unroll
    for (int r = 0; r < 4; ++r) {
        int row = row0 + rbase + r;
        y[(size_t)row * OUTD + col] = acc[r] * norm[row];
    }
}

// ---------------- edge scatter: agg[dst] += y[src] ----------------
// One thread per (edge, 4-feature chunk). Consecutive threads cover the
// same edge's consecutive features -> coalesced within the row gather.
template <int F>
__global__ __launch_bounds__(256) void scatter_kernel(
    const float* __restrict__ y, const int* __restrict__ src,
    const int* __restrict__ dst, float* __restrict__ agg) {
    constexpr int C = F / 4;  // chunks per edge (power of 2)
    long gid = (long)blockIdx.x * 256 + threadIdx.x;
    int e = (int)(gid / C);
    int c = (int)(gid % C);
    if (e >= NEDGES) return;
    int s = src[e], d = dst[e];
    float4 v = *(const float4*)(y + (size_t)s * F + c * 4);
    float* ap = agg + (size_t)d * F + c * 4;
    atomicAdd(ap + 0, v.x);
    atomicAdd(ap + 1, v.y);
    atomicAdd(ap + 2, v.z);
    atomicAdd(ap + 3, v.w);
}

// ---------------- finalize: out = act((agg + y) * norm + b), opt residual ---
// mode 0: out = leaky(v)
// mode 1: out = (xres + leaky(v)) * 0.5
// mode 2: out = v            (final layer, no activation)
template <int F>
__global__ __launch_bounds__(256) void finalize_kernel(
    const float* __restrict__ y, const float* __restrict__ agg,
    const float* __restrict__ norm, const float* __restrict__ bias,
    const float* __restrict__ xres, float* __restrict__ out, int mode) {
    long gid = (long)blockIdx.x * 256 + threadIdx.x;
    if (gid >= (long)NNODES * F) return;
    int n = (int)(gid / F);
    int f = (int)(gid % F);
    float v = (agg[gid] + y[gid]) * norm[n] + bias[f];
    if (mode != 2) v = v >= 0.f ? v : 0.01f * v;
    if (mode == 1) v = (xres[gid] + v) * 0.5f;
    out[gid] = v;
}

extern "C" void kernel_launch(void* const* d_in, const int* in_sizes, int n_in,
                              void* d_out, int out_size, void* d_ws, size_t ws_size,
                              hipStream_t stream) {
    const float* inputs = (const float*)d_in[0];
    const int* edges = (const int*)d_in[1];
    const int* src = edges;            // edges[0,:]
    const int* dst = edges + NEDGES;   // edges[1,:]
    const float* w_in  = (const float*)d_in[2];
    const float* b_in  = (const float*)d_in[3];
    const float* w1    = (const float*)d_in[4];
    const float* b1    = (const float*)d_in[5];
    const float* w2    = (const float*)d_in[6];
    const float* b2    = (const float*)d_in[7];
    const float* w_out = (const float*)d_in[8];
    const float* b_out = (const float*)d_in[9];

    float* out  = (float*)d_out;
    float* xout = out;                                // [N, 64]  (output 0)
    float* x    = out + (size_t)NNODES * OUTDIM;      // [N, 128] (output 1; used as live x)

    char* ws = (char*)d_ws;
    float* normb = (float*)ws;                                    // N floats
    float* y     = (float*)(ws + (size_t)NNODES * sizeof(float)); // N*128
    float* agg   = y + (size_t)NNODES * HDIM;                     // N*128
    float* h     = agg + (size_t)NNODES * HDIM;                   // N*128

    // degree + norm
    hipMemsetAsync(normb, 0, NNODES * sizeof(float), stream);
    deg_kernel<<<(NEDGES + 255) / 256, 256, 0, stream>>>(dst, normb);
    norm_kernel<<<(NNODES + 255) / 256, 256, 0, stream>>>(normb);

    auto conv128 = [&](const float* xin, const float* W, const float* bias,
                       const float* xres, float* outp, int mode) {
        hipMemsetAsync(agg, 0, (size_t)NNODES * HDIM * sizeof(float), stream);
        matmul_norm_kernel<128><<<NNODES / 8, dim3(128, 2), 0, stream>>>(xin, W, normb, y);
        scatter_kernel<128><<<(NEDGES * 32) / 256, 256, 0, stream>>>(y, src, dst, agg);
        finalize_kernel<128><<<((size_t)NNODES * 128) / 256, 256, 0, stream>>>(
            y, agg, normb, bias, xres, outp, mode);
    };

    // input layer
    conv128(inputs, w_in, b_in, nullptr, x, 0);

    // 6 residual blocks
    for (int i = 0; i < 6; ++i) {
        conv128(x, w1 + (size_t)i * HDIM * HDIM, b1 + i * HDIM, nullptr, h, 0);
        conv128(h, w2 + (size_t)i * HDIM * HDIM, b2 + i * HDIM, x, x, 1);
    }

    // output layer (H -> 64, no activation)
    hipMemsetAsync(agg, 0, (size_t)NNODES * OUTDIM * sizeof(float), stream);
    matmul_norm_kernel<64><<<NNODES / 16, dim3(64, 4), 0, stream>>>(x, w_out, normb, y);
    scatter_kernel<64><<<(NEDGES * 16) / 256, 256, 0, stream>>>(y, src, dst, agg);
    finalize_kernel<64><<<((size_t)NNODES * 64) / 256, 256, 0, stream>>>(
        y, agg, normb, b_out, nullptr, xout, 2);
}

// Round 2
// 1903.197 us; speedup vs baseline: 9.9797x; 9.9797x over previous
//
#include <hip/hip_runtime.h>

#define NNODES 50000
#define NEDGES 800000
#define HDIM 128
#define OUTDIM 64

// ---------------- CSR build ----------------
__global__ void count_kernel(const int* __restrict__ dst, int* __restrict__ deg) {
    int e = blockIdx.x * 256 + threadIdx.x;
    if (e < NEDGES) atomicAdd(&deg[dst[e]], 1);
}

// One block of 1024 threads: exclusive scan of deg -> row_ptr, copy to cursor,
// and norm = rsqrt(1+deg).
__global__ __launch_bounds__(1024) void scan_kernel(
    const int* __restrict__ deg, int* __restrict__ row_ptr,
    int* __restrict__ cursor, float* __restrict__ norm) {
    __shared__ int sums[1024];
    const int T = 1024;
    int t = threadIdx.x;
    const int per = (NNODES + T - 1) / T;  // 49
    int start = t * per;
    int end = start + per < NNODES ? start + per : NNODES;
    int s = 0;
    for (int i = start; i < end; ++i) s += deg[i];
    sums[t] = s;
    __syncthreads();
    for (int off = 1; off < T; off <<= 1) {
        int v = (t >= off) ? sums[t - off] : 0;
        __syncthreads();
        sums[t] += v;
        __syncthreads();
    }
    int running = (t == 0) ? 0 : sums[t - 1];
    for (int i = start; i < end; ++i) {
        row_ptr[i] = running;
        cursor[i] = running;
        norm[i] = rsqrtf(1.0f + (float)deg[i]);
        running += deg[i];
    }
    if (t == T - 1) row_ptr[NNODES] = sums[T - 1];
}

__global__ void fill_kernel(const int* __restrict__ src, const int* __restrict__ dst,
                            int* __restrict__ cursor, int* __restrict__ sorted_src) {
    int e = blockIdx.x * 256 + threadIdx.x;
    if (e < NEDGES) {
        int pos = atomicAdd(&cursor[dst[e]], 1);
        sorted_src[pos] = src[e];
    }
}

// ---------------- matmul + norm-scale epilogue: y = (x @ W) * norm[row] ----
template <int OUTD>
__global__ __launch_bounds__(256) void matmul_norm_kernel(
    const float* __restrict__ x, const float* __restrict__ W,
    const float* __restrict__ norm, float* __restrict__ y) {
    constexpr int TY = 256 / OUTD;
    constexpr int RPB = TY * 4;
    __shared__ float xs[RPB][128];
    const int tid = threadIdx.y * OUTD + threadIdx.x;
    const int row0 = blockIdx.x * RPB;
    for (int i = tid; i < RPB * 128; i += 256) {
        int r = i >> 7, k = i & 127;
        xs[r][k] = x[(size_t)(row0 + r) * 128 + k];
    }
    __syncthreads();
    const int col = threadIdx.x;
    const int rbase = threadIdx.y * 4;
    float acc[4] = {0.f, 0.f, 0.f, 0.f};
    for (int k = 0; k < 128; ++k) {
        float wk = W[k * OUTD + col];
#pragma unroll
        for (int r = 0; r < 4; ++r) acc[r] += xs[rbase + r][k] * wk;
    }
#pragma unroll
    for (int r = 0; r < 4; ++r) {
        int row = row0 + rbase + r;
        y[(size_t)row * OUTD + col] = acc[r] * norm[row];
    }
}

// ---------------- fused gather + finalize ----------------
// One wave per node. F=128: 2 floats/lane (float2); F=64: 1 float/lane.
// out = act((sum_{src in-edges} y[src] + y[n]) * norm[n] + b), optional residual.
// mode 0: leaky; mode 1: (xres + leaky)*0.5; mode 2: identity (final layer).
template <int F, int MODE>
__global__ __launch_bounds__(256) void gather_finalize_kernel(
    const float* __restrict__ y, const int* __restrict__ row_ptr,
    const int* __restrict__ sorted_src, const float* __restrict__ norm,
    const float* __restrict__ bias, const float* __restrict__ xres,
    float* __restrict__ out) {
    const int wave = threadIdx.x >> 6;
    const int lane = threadIdx.x & 63;
    const int n = blockIdx.x * 4 + wave;  // NNODES % 4 == 0, grid exact
    const int beg = row_ptr[n];
    const int end = row_ptr[n + 1];

    if (F == 128) {
        float2 acc = {0.f, 0.f}, acc2 = {0.f, 0.f};
        int i = beg;
        for (; i + 1 < end; i += 2) {
            int s0 = sorted_src[i], s1 = sorted_src[i + 1];
            float2 a = *(const float2*)(y + (size_t)s0 * 128 + lane * 2);
            float2 b = *(const float2*)(y + (size_t)s1 * 128 + lane * 2);
            acc.x += a.x; acc.y += a.y;
            acc2.x += b.x; acc2.y += b.y;
        }
        if (i < end) {
            int s0 = sorted_src[i];
            float2 a = *(const float2*)(y + (size_t)s0 * 128 + lane * 2);
            acc.x += a.x; acc.y += a.y;
        }
        acc.x += acc2.x; acc.y += acc2.y;
        float2 self = *(const float2*)(y + (size_t)n * 128 + lane * 2);
        float nm = norm[n];
        float v0 = (acc.x + self.x) * nm + bias[lane * 2];
        float v1 = (acc.y + self.y) * nm + bias[lane * 2 + 1];
        if (MODE != 2) {
            v0 = v0 >= 0.f ? v0 : 0.01f * v0;
            v1 = v1 >= 0.f ? v1 : 0.01f * v1;
        }
        if (MODE == 1) {
            const float2 xr = *(const float2*)(xres + (size_t)n * 128 + lane * 2);
            v0 = (xr.x + v0) * 0.5f;
            v1 = (xr.y + v1) * 0.5f;
        }
        float2 o = {v0, v1};
        *(float2*)(out + (size_t)n * 128 + lane * 2) = o;
    } else {
        float acc = 0.f, acc2 = 0.f;
        int i = beg;
        for (; i + 1 < end; i += 2) {
            int s0 = sorted_src[i], s1 = sorted_src[i + 1];
            acc += y[(size_t)s0 * 64 + lane];
            acc2 += y[(size_t)s1 * 64 + lane];
        }
        if (i < end) acc += y[(size_t)sorted_src[i] * 64 + lane];
        acc += acc2;
        float self = y[(size_t)n * 64 + lane];
        float v = (acc + self) * norm[n] + bias[lane];
        if (MODE != 2) v = v >= 0.f ? v : 0.01f * v;
        out[(size_t)n * 64 + lane] = v;
    }
}

extern "C" void kernel_launch(void* const* d_in, const int* in_sizes, int n_in,
                              void* d_out, int out_size, void* d_ws, size_t ws_size,
                              hipStream_t stream) {
    const float* inputs = (const float*)d_in[0];
    const int* edges = (const int*)d_in[1];
    const int* src = edges;            // edges[0,:]
    const int* dst = edges + NEDGES;   // edges[1,:]
    const float* w_in  = (const float*)d_in[2];
    const float* b_in  = (const float*)d_in[3];
    const float* w1    = (const float*)d_in[4];
    const float* b1    = (const float*)d_in[5];
    const float* w2    = (const float*)d_in[6];
    const float* b2    = (const float*)d_in[7];
    const float* w_out = (const float*)d_in[8];
    const float* b_out = (const float*)d_in[9];

    float* out  = (float*)d_out;
    float* xout = out;                                // [N, 64]  (output 0)
    float* x    = out + (size_t)NNODES * OUTDIM;      // [N, 128] (output 1; live x)

    char* ws = (char*)d_ws;
    int* deg        = (int*)ws;                        // N
    int* row_ptr    = deg + NNODES;                    // N+1
    int* cursor     = row_ptr + NNODES + 1;            // N
    int* sorted_src = cursor + NNODES;                 // E
    float* normb    = (float*)(sorted_src + NEDGES);   // N
    float* y        = normb + NNODES;                  // N*128
    float* h        = y + (size_t)NNODES * HDIM;       // N*128

    // ---- CSR + norm (once per call) ----
    hipMemsetAsync(deg, 0, NNODES * sizeof(int), stream);
    count_kernel<<<(NEDGES + 255) / 256, 256, 0, stream>>>(dst, deg);
    scan_kernel<<<1, 1024, 0, stream>>>(deg, row_ptr, cursor, normb);
    fill_kernel<<<(NEDGES + 255) / 256, 256, 0, stream>>>(src, dst, cursor, sorted_src);

    auto conv128 = [&](const float* xin, const float* W, const float* bias,
                       const float* xres, float* outp, int mode) {
        matmul_norm_kernel<128><<<NNODES / 8, dim3(128, 2), 0, stream>>>(xin, W, normb, y);
        if (mode == 0)
            gather_finalize_kernel<128, 0><<<NNODES / 4, 256, 0, stream>>>(
                y, row_ptr, sorted_src, normb, bias, nullptr, outp);
        else
            gather_finalize_kernel<128, 1><<<NNODES / 4, 256, 0, stream>>>(
                y, row_ptr, sorted_src, normb, bias, xres, outp);
    };

    // input layer
    conv128(inputs, w_in, b_in, nullptr, x, 0);

    // 6 residual blocks
    for (int i = 0; i < 6; ++i) {
        conv128(x, w1 + (size_t)i * HDIM * HDIM, b1 + i * HDIM, nullptr, h, 0);
        conv128(h, w2 + (size_t)i * HDIM * HDIM, b2 + i * HDIM, x, x, 1);
    }

    // output layer (H -> 64, no activation)
    matmul_norm_kernel<64><<<NNODES / 16, dim3(64, 4), 0, stream>>>(x, w_out, normb, y);
    gather_finalize_kernel<64, 2><<<NNODES / 4, 256, 0, stream>>>(
        y, row_ptr, sorted_src, normb, b_out, nullptr, xout);
}

// Round 3
// 1594.618 us; speedup vs baseline: 11.9109x; 1.1935x over previous
//
#include <hip/hip_runtime.h>

#define NNODES 50000
#define NPAD   50048   // 391 * 128
#define NEDGES 800000
#define HDIM 128
#define OUTDIM 64

typedef short short8 __attribute__((ext_vector_type(8)));
typedef float f32x4 __attribute__((ext_vector_type(4)));

__device__ __forceinline__ unsigned short f2bf(float f) {
    unsigned int u = __builtin_bit_cast(unsigned int, f);
    unsigned int r = (u + 0x7FFFu + ((u >> 16) & 1u)) >> 16;
    return (unsigned short)r;
}
__device__ __forceinline__ float bf2f(unsigned short b) {
    unsigned int u = ((unsigned int)b) << 16;
    return __builtin_bit_cast(float, u);
}

// ---------------- CSR build ----------------
__global__ void count_kernel(const int* __restrict__ dst, int* __restrict__ deg) {
    int e = blockIdx.x * 256 + threadIdx.x;
    if (e < NEDGES) atomicAdd(&deg[dst[e]], 1);
}

__global__ __launch_bounds__(256) void bsum_kernel(const int* __restrict__ deg,
                                                   int* __restrict__ bsum) {
    __shared__ int red[256];
    int i = blockIdx.x * 256 + threadIdx.x;
    red[threadIdx.x] = (i < NNODES) ? deg[i] : 0;
    __syncthreads();
    for (int off = 128; off; off >>= 1) {
        if (threadIdx.x < off) red[threadIdx.x] += red[threadIdx.x + off];
        __syncthreads();
    }
    if (threadIdx.x == 0) bsum[blockIdx.x] = red[0];
}

// 1 block: exclusive scan of 196 block sums
__global__ __launch_bounds__(256) void bscan_kernel(const int* __restrict__ bsum,
                                                    int* __restrict__ bofs) {
    __shared__ int s[256];
    int t = threadIdx.x;
    int v = (t < 196) ? bsum[t] : 0;
    s[t] = v;
    __syncthreads();
    for (int off = 1; off < 256; off <<= 1) {
        int u = (t >= off) ? s[t - off] : 0;
        __syncthreads();
        s[t] += u;
        __syncthreads();
    }
    if (t < 196) bofs[t] = s[t] - v;  // exclusive
}

__global__ __launch_bounds__(256) void emit_kernel(
    const int* __restrict__ deg, const int* __restrict__ bofs,
    int* __restrict__ row_ptr, int* __restrict__ cursor, float* __restrict__ norm) {
    __shared__ int s[256];
    int t = threadIdx.x;
    int i = blockIdx.x * 256 + t;
    int v = (i < NNODES) ? deg[i] : 0;
    s[t] = v;
    __syncthreads();
    for (int off = 1; off < 256; off <<= 1) {
        int u = (t >= off) ? s[t - off] : 0;
        __syncthreads();
        s[t] += u;
        __syncthreads();
    }
    int excl = s[t] - v + bofs[blockIdx.x];
    if (i < NNODES) {
        row_ptr[i] = excl;
        cursor[i] = excl;
        norm[i] = rsqrtf(1.0f + (float)v);
    }
    if (i == NNODES - 1) row_ptr[NNODES] = NEDGES;
}

__global__ void fill_kernel(const int* __restrict__ src, const int* __restrict__ dst,
                            int* __restrict__ cursor, int* __restrict__ sorted_src) {
    int e = blockIdx.x * 256 + threadIdx.x;
    if (e < NEDGES) {
        int pos = atomicAdd(&cursor[dst[e]], 1);
        sorted_src[pos] = src[e];
    }
}

// ---------------- weight prep: split fp32 W[K][Nc] -> WT[Nc][384] bf16 -------
// WT[n][k] : k in [0,128) = hi(W[k][n]); [128,256) = hi (pairs with x_lo);
//            [256,384) = lo(W[k][n])    (pairs with x_hi)
// slots: w_in | w1[0..5] | w2[0..5] | w_out ; H-slot = 49152 ushorts.
__global__ __launch_bounds__(256) void prep_w_kernel(
    const float* __restrict__ w_in, const float* __restrict__ w1,
    const float* __restrict__ w2, const float* __restrict__ w_out,
    unsigned short* __restrict__ wT) {
    int idx = blockIdx.x * 256 + threadIdx.x;  // total 221184 = 864*256
    const float* W;
    unsigned short* o;
    int Nc, e;
    if (idx < 16384) {
        W = w_in; o = wT; Nc = 128; e = idx;
    } else if (idx < 16384 + 98304) {
        int j = idx - 16384; int m = j >> 14; e = j & 16383;
        W = w1 + ((size_t)m << 14); o = wT + (size_t)(1 + m) * 49152; Nc = 128;
    } else if (idx < 16384 + 196608) {
        int j = idx - 16384 - 98304; int m = j >> 14; e = j & 16383;
        W = w2 + ((size_t)m << 14); o = wT + (size_t)(7 + m) * 49152; Nc = 128;
    } else {
        e = idx - 212992;
        W = w_out; o = wT + (size_t)13 * 49152; Nc = 64;
    }
    int k = (Nc == 128) ? (e >> 7) : (e >> 6);
    int n = (Nc == 128) ? (e & 127) : (e & 63);
    float v = W[e];
    unsigned short h = f2bf(v);
    unsigned short l = f2bf(v - bf2f(h));
    o[(size_t)n * 384 + k] = h;
    o[(size_t)n * 384 + 128 + k] = h;
    o[(size_t)n * 384 + 256 + k] = l;
}

// ---------------- x split: xcat[row][0:128]=hi(x*norm), [128:256]=lo ---------
__global__ __launch_bounds__(256) void split_x_kernel(
    const float* __restrict__ x, const float* __restrict__ norm,
    unsigned short* __restrict__ xcat) {
    int gid = blockIdx.x * 256 + threadIdx.x;  // NPAD*64 threads, 2 elems each
    int row = gid >> 6;
    int kk = (gid & 63) * 2;
    float2 v = {0.f, 0.f};
    float nm = 0.f;
    if (row < NNODES) {
        v = *(const float2*)(x + (size_t)row * 128 + kk);
        nm = norm[row];
    }
    float a0 = v.x * nm, a1 = v.y * nm;
    unsigned short h0 = f2bf(a0), h1 = f2bf(a1);
    unsigned short l0 = f2bf(a0 - bf2f(h0)), l1 = f2bf(a1 - bf2f(h1));
    unsigned int hi = (unsigned int)h0 | ((unsigned int)h1 << 16);
    unsigned int lo = (unsigned int)l0 | ((unsigned int)l1 << 16);
    *(unsigned int*)(xcat + (size_t)row * 256 + kk) = hi;
    *(unsigned int*)(xcat + (size_t)row * 256 + 128 + kk) = lo;
}

// ---------------- MFMA GEMM: y[M,NCOLS] = xcat(K=384 via remap) @ WT^T -------
// block: 128 rows x NCOLS cols, 256 threads (4 waves). 16x16x32 bf16 MFMA.
template <int NCOLS>
__global__ __launch_bounds__(256) void gemm_kernel(
    const unsigned short* __restrict__ xcat, const unsigned short* __restrict__ wT,
    float* __restrict__ y) {
    constexpr int MT = (NCOLS == 128) ? 4 : 2;
    __shared__ unsigned short Alds[128 * 32];
    __shared__ unsigned short Blds[NCOLS * 32];
    const int t = threadIdx.x;
    const int wave = t >> 6, lane = t & 63, quad = lane >> 4, l16 = lane & 15;
    const int row0 = blockIdx.x * 128;
    const int wm = (NCOLS == 128) ? (wave >> 1) * 64 : wave * 32;
    const int wn = (NCOLS == 128) ? (wave & 1) * 64 : 0;

    f32x4 acc[MT][4];
#pragma unroll
    for (int mt = 0; mt < MT; ++mt)
#pragma unroll
        for (int nt = 0; nt < 4; ++nt) acc[mt][nt] = (f32x4){0.f, 0.f, 0.f, 0.f};

    for (int ks = 0; ks < 12; ++ks) {
        const int k0 = ks * 32;
        const int keff = (k0 >= 256) ? (k0 - 256) : k0;  // A slot2 re-reads hi
        __syncthreads();
#pragma unroll
        for (int i = 0; i < 2; ++i) {  // A: 512 x 16B chunks
            int c = i * 256 + t;
            int m = c >> 2, q = c & 3;
            const unsigned short* gp = xcat + (size_t)(row0 + m) * 256 + keff + q * 8;
            unsigned short* lp = Alds + (size_t)c * 8;
            __builtin_amdgcn_global_load_lds(
                (const __attribute__((address_space(1))) void*)gp,
                (__attribute__((address_space(3))) void*)lp, 16, 0, 0);
        }
#pragma unroll
        for (int i = 0; i < (NCOLS * 4) / 256; ++i) {  // B: NCOLS*4 chunks
            int c = i * 256 + t;
            int n = c >> 2, q = c & 3;
            const unsigned short* gp = wT + (size_t)n * 384 + k0 + q * 8;
            unsigned short* lp = Blds + (size_t)c * 8;
            __builtin_amdgcn_global_load_lds(
                (const __attribute__((address_space(1))) void*)gp,
                (__attribute__((address_space(3))) void*)lp, 16, 0, 0);
        }
        __syncthreads();

        short8 a[MT], b[4];
#pragma unroll
        for (int mt = 0; mt < MT; ++mt)
            a[mt] = *(const short8*)(Alds + (size_t)(wm + mt * 16 + l16) * 32 + quad * 8);
#pragma unroll
        for (int nt = 0; nt < 4; ++nt)
            b[nt] = *(const short8*)(Blds + (size_t)(wn + nt * 16 + l16) * 32 + quad * 8);
#pragma unroll
        for (int mt = 0; mt < MT; ++mt)
#pragma unroll
            for (int nt = 0; nt < 4; ++nt)
                acc[mt][nt] = __builtin_amdgcn_mfma_f32_16x16x32_bf16(
                    a[mt], b[nt], acc[mt][nt], 0, 0, 0);
    }

    // epilogue: C/D layout col=l16, row=quad*4+r
#pragma unroll
    for (int mt = 0; mt < MT; ++mt) {
        int mbase = row0 + wm + mt * 16 + quad * 4;
#pragma unroll
        for (int nt = 0; nt < 4; ++nt) {
            int col = wn + nt * 16 + l16;
#pragma unroll
            for (int r = 0; r < 4; ++r) {
                int row = mbase + r;
                if (row < NNODES) y[(size_t)row * NCOLS + col] = acc[mt][nt][r];
            }
        }
    }
}

// ---------------- fused gather + finalize ----------------
template <int F, int MODE>
__global__ __launch_bounds__(256) void gather_finalize_kernel(
    const float* __restrict__ y, const int* __restrict__ row_ptr,
    const int* __restrict__ sorted_src, const float* __restrict__ norm,
    const float* __restrict__ bias, const float* __restrict__ xres,
    float* __restrict__ out) {
    const int wave = threadIdx.x >> 6;
    const int lane = threadIdx.x & 63;
    const int n = blockIdx.x * 4 + wave;
    const int beg = row_ptr[n];
    const int end = row_ptr[n + 1];

    if (F == 128) {
        float2 acc = {0.f, 0.f}, acc2 = {0.f, 0.f};
        int i = beg;
        for (; i + 1 < end; i += 2) {
            int s0 = sorted_src[i], s1 = sorted_src[i + 1];
            float2 a = *(const float2*)(y + (size_t)s0 * 128 + lane * 2);
            float2 b = *(const float2*)(y + (size_t)s1 * 128 + lane * 2);
            acc.x += a.x; acc.y += a.y;
            acc2.x += b.x; acc2.y += b.y;
        }
        if (i < end) {
            int s0 = sorted_src[i];
            float2 a = *(const float2*)(y + (size_t)s0 * 128 + lane * 2);
            acc.x += a.x; acc.y += a.y;
        }
        acc.x += acc2.x; acc.y += acc2.y;
        float2 self = *(const float2*)(y + (size_t)n * 128 + lane * 2);
        float nm = norm[n];
        float v0 = (acc.x + self.x) * nm + bias[lane * 2];
        float v1 = (acc.y + self.y) * nm + bias[lane * 2 + 1];
        if (MODE != 2) {
            v0 = v0 >= 0.f ? v0 : 0.01f * v0;
            v1 = v1 >= 0.f ? v1 : 0.01f * v1;
        }
        if (MODE == 1) {
            const float2 xr = *(const float2*)(xres + (size_t)n * 128 + lane * 2);
            v0 = (xr.x + v0) * 0.5f;
            v1 = (xr.y + v1) * 0.5f;
        }
        float2 o = {v0, v1};
        *(float2*)(out + (size_t)n * 128 + lane * 2) = o;
    } else {
        float acc = 0.f, acc2 = 0.f;
        int i = beg;
        for (; i + 1 < end; i += 2) {
            int s0 = sorted_src[i], s1 = sorted_src[i + 1];
            acc += y[(size_t)s0 * 64 + lane];
            acc2 += y[(size_t)s1 * 64 + lane];
        }
        if (i < end) acc += y[(size_t)sorted_src[i] * 64 + lane];
        acc += acc2;
        float self = y[(size_t)n * 64 + lane];
        float v = (acc + self) * norm[n] + bias[lane];
        if (MODE != 2) v = v >= 0.f ? v : 0.01f * v;
        out[(size_t)n * 64 + lane] = v;
    }
}

extern "C" void kernel_launch(void* const* d_in, const int* in_sizes, int n_in,
                              void* d_out, int out_size, void* d_ws, size_t ws_size,
                              hipStream_t stream) {
    const float* inputs = (const float*)d_in[0];
    const int* edges = (const int*)d_in[1];
    const int* src = edges;
    const int* dst = edges + NEDGES;
    const float* w_in  = (const float*)d_in[2];
    const float* b_in  = (const float*)d_in[3];
    const float* w1    = (const float*)d_in[4];
    const float* b1    = (const float*)d_in[5];
    const float* w2    = (const float*)d_in[6];
    const float* b2    = (const float*)d_in[7];
    const float* w_out = (const float*)d_in[8];
    const float* b_out = (const float*)d_in[9];

    float* out  = (float*)d_out;
    float* xout = out;                                // [N, 64]
    float* x    = out + (size_t)NNODES * OUTDIM;      // [N, 128] live x

    char* p = (char*)d_ws;
    auto alloc = [&](size_t bytes) {
        char* r = p;
        p += (bytes + 63) & ~(size_t)63;
        return r;
    };
    int* deg        = (int*)alloc(NNODES * 4);
    int* row_ptr    = (int*)alloc((NNODES + 1) * 4);
    int* cursor     = (int*)alloc(NNODES * 4);
    int* bsum       = (int*)alloc(256 * 4);
    int* bofs       = (int*)alloc(256 * 4);
    int* sorted_src = (int*)alloc(NEDGES * 4);
    float* normb    = (float*)alloc(NNODES * 4);
    unsigned short* wT   = (unsigned short*)alloc((size_t)663552 * 2);   // 13*49152+24576
    unsigned short* xcat = (unsigned short*)alloc((size_t)NPAD * 256 * 2);
    float* y        = (float*)alloc((size_t)NNODES * HDIM * 4);
    float* h        = (float*)alloc((size_t)NNODES * HDIM * 4);

    // ---- CSR + norm + weight prep ----
    hipMemsetAsync(deg, 0, NNODES * sizeof(int), stream);
    count_kernel<<<(NEDGES + 255) / 256, 256, 0, stream>>>(dst, deg);
    bsum_kernel<<<196, 256, 0, stream>>>(deg, bsum);
    bscan_kernel<<<1, 256, 0, stream>>>(bsum, bofs);
    emit_kernel<<<196, 256, 0, stream>>>(deg, bofs, row_ptr, cursor, normb);
    fill_kernel<<<(NEDGES + 255) / 256, 256, 0, stream>>>(src, dst, cursor, sorted_src);
    prep_w_kernel<<<864, 256, 0, stream>>>(w_in, w1, w2, w_out, wT);

    auto conv128 = [&](const float* xin, int wslot, const float* bias,
                       const float* xres, float* outp, int mode) {
        split_x_kernel<<<(NPAD * 64) / 256, 256, 0, stream>>>(xin, normb, xcat);
        gemm_kernel<128><<<NPAD / 128, 256, 0, stream>>>(xcat, wT + (size_t)wslot * 49152, y);
        if (mode == 0)
            gather_finalize_kernel<128, 0><<<NNODES / 4, 256, 0, stream>>>(
                y, row_ptr, sorted_src, normb, bias, nullptr, outp);
        else
            gather_finalize_kernel<128, 1><<<NNODES / 4, 256, 0, stream>>>(
                y, row_ptr, sorted_src, normb, bias, xres, outp);
    };

    // input layer
    conv128(inputs, 0, b_in, nullptr, x, 0);

    // 6 residual blocks
    for (int i = 0; i < 6; ++i) {
        conv128(x, 1 + i, b1 + i * HDIM, nullptr, h, 0);
        conv128(h, 7 + i, b2 + i * HDIM, x, x, 1);
    }

    // output layer (H -> 64, no activation)
    split_x_kernel<<<(NPAD * 64) / 256, 256, 0, stream>>>(x, normb, xcat);
    gemm_kernel<64><<<NPAD / 128, 256, 0, stream>>>(xcat, wT + (size_t)13 * 49152, y);
    gather_finalize_kernel<64, 2><<<NNODES / 4, 256, 0, stream>>>(
        y, row_ptr, sorted_src, normb, b_out, nullptr, xout);
}

// Round 4
// 1383.753 us; speedup vs baseline: 13.7259x; 1.1524x over previous
//
#include <hip/hip_runtime.h>

#define NNODES 50000
#define NPAD   50048   // 391 * 128
#define NEDGES 800000
#define HDIM 128
#define OUTDIM 64

typedef short short8 __attribute__((ext_vector_type(8)));
typedef float f32x4 __attribute__((ext_vector_type(4)));
typedef unsigned short us4 __attribute__((ext_vector_type(4)));

__device__ __forceinline__ unsigned short f2bf(float f) {
    unsigned int u = __builtin_bit_cast(unsigned int, f);
    unsigned int r = (u + 0x7FFFu + ((u >> 16) & 1u)) >> 16;
    return (unsigned short)r;
}
__device__ __forceinline__ float bf2f(unsigned short b) {
    unsigned int u = ((unsigned int)b) << 16;
    return __builtin_bit_cast(float, u);
}

// ---------------- CSR build ----------------
__global__ void count_kernel(const int* __restrict__ dst, int* __restrict__ deg) {
    int e = blockIdx.x * 256 + threadIdx.x;
    if (e < NEDGES) atomicAdd(&deg[dst[e]], 1);
}

__global__ __launch_bounds__(256) void bsum_kernel(const int* __restrict__ deg,
                                                   int* __restrict__ bsum) {
    __shared__ int red[256];
    int i = blockIdx.x * 256 + threadIdx.x;
    red[threadIdx.x] = (i < NNODES) ? deg[i] : 0;
    __syncthreads();
    for (int off = 128; off; off >>= 1) {
        if (threadIdx.x < off) red[threadIdx.x] += red[threadIdx.x + off];
        __syncthreads();
    }
    if (threadIdx.x == 0) bsum[blockIdx.x] = red[0];
}

__global__ __launch_bounds__(256) void bscan_kernel(const int* __restrict__ bsum,
                                                    int* __restrict__ bofs) {
    __shared__ int s[256];
    int t = threadIdx.x;
    int v = (t < 196) ? bsum[t] : 0;
    s[t] = v;
    __syncthreads();
    for (int off = 1; off < 256; off <<= 1) {
        int u = (t >= off) ? s[t - off] : 0;
        __syncthreads();
        s[t] += u;
        __syncthreads();
    }
    if (t < 196) bofs[t] = s[t] - v;  // exclusive
}

__global__ __launch_bounds__(256) void emit_kernel(
    const int* __restrict__ deg, const int* __restrict__ bofs,
    int* __restrict__ row_ptr, int* __restrict__ cursor, float* __restrict__ norm) {
    __shared__ int s[256];
    int t = threadIdx.x;
    int i = blockIdx.x * 256 + t;
    int v = (i < NNODES) ? deg[i] : 0;
    s[t] = v;
    __syncthreads();
    for (int off = 1; off < 256; off <<= 1) {
        int u = (t >= off) ? s[t - off] : 0;
        __syncthreads();
        s[t] += u;
        __syncthreads();
    }
    int excl = s[t] - v + bofs[blockIdx.x];
    if (i < NNODES) {
        row_ptr[i] = excl;
        cursor[i] = excl;
        norm[i] = rsqrtf(1.0f + (float)v);
    }
    if (i == NNODES - 1) row_ptr[NNODES] = NEDGES;
}

__global__ void fill_kernel(const int* __restrict__ src, const int* __restrict__ dst,
                            int* __restrict__ cursor, int* __restrict__ sorted_src) {
    int e = blockIdx.x * 256 + threadIdx.x;
    if (e < NEDGES) {
        int pos = atomicAdd(&cursor[dst[e]], 1);
        sorted_src[pos] = src[e];
    }
}

// ---------------- weight prep (bf16 hi/lo split, transposed) ----------------
__global__ __launch_bounds__(256) void prep_w_kernel(
    const float* __restrict__ w_in, const float* __restrict__ w1,
    const float* __restrict__ w2, const float* __restrict__ w_out,
    unsigned short* __restrict__ wT) {
    int idx = blockIdx.x * 256 + threadIdx.x;  // total 221184 = 864*256
    const float* W;
    unsigned short* o;
    int Nc, e;
    if (idx < 16384) {
        W = w_in; o = wT; Nc = 128; e = idx;
    } else if (idx < 16384 + 98304) {
        int j = idx - 16384; int m = j >> 14; e = j & 16383;
        W = w1 + ((size_t)m << 14); o = wT + (size_t)(1 + m) * 49152; Nc = 128;
    } else if (idx < 16384 + 196608) {
        int j = idx - 16384 - 98304; int m = j >> 14; e = j & 16383;
        W = w2 + ((size_t)m << 14); o = wT + (size_t)(7 + m) * 49152; Nc = 128;
    } else {
        e = idx - 212992;
        W = w_out; o = wT + (size_t)13 * 49152; Nc = 64;
    }
    int k = (Nc == 128) ? (e >> 7) : (e >> 6);
    int n = (Nc == 128) ? (e & 127) : (e & 63);
    float v = W[e];
    unsigned short h = f2bf(v);
    unsigned short l = f2bf(v - bf2f(h));
    o[(size_t)n * 384 + k] = h;
    o[(size_t)n * 384 + 128 + k] = h;
    o[(size_t)n * 384 + 256 + k] = l;
}

// ---------------- x split (input layer only) ----------------
__global__ __launch_bounds__(256) void split_x_kernel(
    const float* __restrict__ x, const float* __restrict__ norm,
    unsigned short* __restrict__ xcat) {
    int gid = blockIdx.x * 256 + threadIdx.x;
    int row = gid >> 6;
    int kk = (gid & 63) * 2;
    float2 v = {0.f, 0.f};
    float nm = 0.f;
    if (row < NNODES) {
        v = *(const float2*)(x + (size_t)row * 128 + kk);
        nm = norm[row];
    }
    float a0 = v.x * nm, a1 = v.y * nm;
    unsigned short h0 = f2bf(a0), h1 = f2bf(a1);
    unsigned short l0 = f2bf(a0 - bf2f(h0)), l1 = f2bf(a1 - bf2f(h1));
    unsigned int hi = (unsigned int)h0 | ((unsigned int)h1 << 16);
    unsigned int lo = (unsigned int)l0 | ((unsigned int)l1 << 16);
    *(unsigned int*)(xcat + (size_t)row * 256 + kk) = hi;
    *(unsigned int*)(xcat + (size_t)row * 256 + 128 + kk) = lo;
}

// ---------------- MFMA GEMM: y[M,NCOLS] = xcat(K=384 via remap) @ WT^T -------
template <int NCOLS>
__global__ __launch_bounds__(256) void gemm_kernel(
    const unsigned short* __restrict__ xcat, const unsigned short* __restrict__ wT,
    float* __restrict__ y) {
    constexpr int MT = (NCOLS == 128) ? 4 : 2;
    __shared__ unsigned short Alds[128 * 32];
    __shared__ unsigned short Blds[NCOLS * 32];
    const int t = threadIdx.x;
    const int wave = t >> 6, lane = t & 63, quad = lane >> 4, l16 = lane & 15;
    const int row0 = blockIdx.x * 128;
    const int wm = (NCOLS == 128) ? (wave >> 1) * 64 : wave * 32;
    const int wn = (NCOLS == 128) ? (wave & 1) * 64 : 0;

    f32x4 acc[MT][4];
#pragma unroll
    for (int mt = 0; mt < MT; ++mt)
#pragma unroll
        for (int nt = 0; nt < 4; ++nt) acc[mt][nt] = (f32x4){0.f, 0.f, 0.f, 0.f};

    for (int ks = 0; ks < 12; ++ks) {
        const int k0 = ks * 32;
        const int keff = (k0 >= 256) ? (k0 - 256) : k0;  // A slot2 re-reads hi
        __syncthreads();
#pragma unroll
        for (int i = 0; i < 2; ++i) {
            int c = i * 256 + t;
            int m = c >> 2, q = c & 3;
            const unsigned short* gp = xcat + (size_t)(row0 + m) * 256 + keff + q * 8;
            unsigned short* lp = Alds + (size_t)c * 8;
            __builtin_amdgcn_global_load_lds(
                (const __attribute__((address_space(1))) void*)gp,
                (__attribute__((address_space(3))) void*)lp, 16, 0, 0);
        }
#pragma unroll
        for (int i = 0; i < (NCOLS * 4) / 256; ++i) {
            int c = i * 256 + t;
            int n = c >> 2, q = c & 3;
            const unsigned short* gp = wT + (size_t)n * 384 + k0 + q * 8;
            unsigned short* lp = Blds + (size_t)c * 8;
            __builtin_amdgcn_global_load_lds(
                (const __attribute__((address_space(1))) void*)gp,
                (__attribute__((address_space(3))) void*)lp, 16, 0, 0);
        }
        __syncthreads();

        short8 a[MT], b[4];
#pragma unroll
        for (int mt = 0; mt < MT; ++mt)
            a[mt] = *(const short8*)(Alds + (size_t)(wm + mt * 16 + l16) * 32 + quad * 8);
#pragma unroll
        for (int nt = 0; nt < 4; ++nt)
            b[nt] = *(const short8*)(Blds + (size_t)(wn + nt * 16 + l16) * 32 + quad * 8);
#pragma unroll
        for (int mt = 0; mt < MT; ++mt)
#pragma unroll
            for (int nt = 0; nt < 4; ++nt)
                acc[mt][nt] = __builtin_amdgcn_mfma_f32_16x16x32_bf16(
                    a[mt], b[nt], acc[mt][nt], 0, 0, 0);
    }

#pragma unroll
    for (int mt = 0; mt < MT; ++mt) {
        int mbase = row0 + wm + mt * 16 + quad * 4;
#pragma unroll
        for (int nt = 0; nt < 4; ++nt) {
            int col = wn + nt * 16 + l16;
#pragma unroll
            for (int r = 0; r < 4; ++r) {
                int row = mbase + r;
                if (row < NNODES) y[(size_t)row * NCOLS + col] = acc[mt][nt][r];
            }
        }
    }
}

// ---------------- fused gather + finalize + bf16 split (F=128) ----------------
// One wave per node. Half-wave (32 lanes x float4) reads one full 512B row per
// edge; 4-deep unroll -> 4 x 2KB row loads in flight per wave. Cross-half
// reduction via shfl_xor(32). Epilogue computes v = act((sum+self)*norm + b)
// [+ residual], writes fp32 out (if WOUT) and xcat = hi/lo split of v*norm.
template <int MODE, bool WOUT>  // MODE 0: plain leaky; 1: residual
__global__ __launch_bounds__(256) void gather_fin128(
    const float* __restrict__ y, const int* __restrict__ row_ptr,
    const int* __restrict__ sorted_src, const float* __restrict__ norm,
    const float* __restrict__ bias, const float* __restrict__ xres,
    float* __restrict__ out, unsigned short* __restrict__ xcat) {
    const int wave = threadIdx.x >> 6;
    const int lane = threadIdx.x & 63;
    const int half = lane >> 5;
    const int l32 = lane & 31;
    const int n = blockIdx.x * 4 + wave;
    const int beg = row_ptr[n];
    const int end = row_ptr[n + 1];

    f32x4 acc0 = {0.f, 0.f, 0.f, 0.f}, acc1 = acc0, acc2 = acc0, acc3 = acc0;
    int i = beg + half;
    for (; i + 6 < end; i += 8) {
        int s0 = sorted_src[i];
        int s1 = sorted_src[i + 2];
        int s2 = sorted_src[i + 4];
        int s3 = sorted_src[i + 6];
        f32x4 a0 = *(const f32x4*)(y + (size_t)s0 * 128 + l32 * 4);
        f32x4 a1 = *(const f32x4*)(y + (size_t)s1 * 128 + l32 * 4);
        f32x4 a2 = *(const f32x4*)(y + (size_t)s2 * 128 + l32 * 4);
        f32x4 a3 = *(const f32x4*)(y + (size_t)s3 * 128 + l32 * 4);
        acc0 += a0;
        acc1 += a1;
        acc2 += a2;
        acc3 += a3;
    }
    for (; i < end; i += 2) {
        int s = sorted_src[i];
        acc0 += *(const f32x4*)(y + (size_t)s * 128 + l32 * 4);
    }
    acc0 += acc1;
    acc2 += acc3;
    acc0 += acc2;
    // cross-half reduce: both halves end with the full sum
    acc0[0] += __shfl_xor(acc0[0], 32, 64);
    acc0[1] += __shfl_xor(acc0[1], 32, 64);
    acc0[2] += __shfl_xor(acc0[2], 32, 64);
    acc0[3] += __shfl_xor(acc0[3], 32, 64);

    const f32x4 self = *(const f32x4*)(y + (size_t)n * 128 + l32 * 4);
    const f32x4 bi = *(const f32x4*)(bias + l32 * 4);
    const float nm = norm[n];
    f32x4 v;
#pragma unroll
    for (int j = 0; j < 4; ++j) {
        float t = (acc0[j] + self[j]) * nm + bi[j];
        v[j] = t >= 0.f ? t : 0.01f * t;
    }
    if (MODE == 1) {
        const f32x4 xr = *(const f32x4*)(xres + (size_t)n * 128 + l32 * 4);
#pragma unroll
        for (int j = 0; j < 4; ++j) v[j] = (xr[j] + v[j]) * 0.5f;
    }
    if (WOUT && half == 0) {
        *(f32x4*)(out + (size_t)n * 128 + l32 * 4) = v;
    }
    // xcat = hi/lo split of v*norm; half 0 writes hi, half 1 writes lo
    us4 pk;
#pragma unroll
    for (int j = 0; j < 4; ++j) {
        float s = v[j] * nm;
        unsigned short h = f2bf(s);
        unsigned short l = f2bf(s - bf2f(h));
        pk[j] = half ? l : h;
    }
    *(us4*)(xcat + (size_t)n * 256 + half * 128 + l32 * 4) = pk;
}

// ---------------- final gather (F=64, identity) ----------------
__global__ __launch_bounds__(256) void gather_fin64(
    const float* __restrict__ y, const int* __restrict__ row_ptr,
    const int* __restrict__ sorted_src, const float* __restrict__ norm,
    const float* __restrict__ bias, float* __restrict__ out) {
    const int wave = threadIdx.x >> 6;
    const int lane = threadIdx.x & 63;
    const int half = lane >> 5;
    const int l32 = lane & 31;
    const int n = blockIdx.x * 4 + wave;
    const int beg = row_ptr[n];
    const int end = row_ptr[n + 1];
    float2 acc0 = {0.f, 0.f}, acc1 = {0.f, 0.f};
    int i = beg + half;
    for (; i + 2 < end; i += 4) {
        int s0 = sorted_src[i];
        int s1 = sorted_src[i + 2];
        float2 a = *(const float2*)(y + (size_t)s0 * 64 + l32 * 2);
        float2 b = *(const float2*)(y + (size_t)s1 * 64 + l32 * 2);
        acc0.x += a.x; acc0.y += a.y;
        acc1.x += b.x; acc1.y += b.y;
    }
    for (; i < end; i += 2) {
        int s = sorted_src[i];
        float2 a = *(const float2*)(y + (size_t)s * 64 + l32 * 2);
        acc0.x += a.x; acc0.y += a.y;
    }
    acc0.x += acc1.x; acc0.y += acc1.y;
    acc0.x += __shfl_xor(acc0.x, 32, 64);
    acc0.y += __shfl_xor(acc0.y, 32, 64);
    if (half == 0) {
        float2 self = *(const float2*)(y + (size_t)n * 64 + l32 * 2);
        float nm = norm[n];
        float2 o;
        o.x = (acc0.x + self.x) * nm + bias[l32 * 2];
        o.y = (acc0.y + self.y) * nm + bias[l32 * 2 + 1];
        *(float2*)(out + (size_t)n * 64 + l32 * 2) = o;
    }
}

extern "C" void kernel_launch(void* const* d_in, const int* in_sizes, int n_in,
                              void* d_out, int out_size, void* d_ws, size_t ws_size,
                              hipStream_t stream) {
    const float* inputs = (const float*)d_in[0];
    const int* edges = (const int*)d_in[1];
    const int* src = edges;
    const int* dst = edges + NEDGES;
    const float* w_in  = (const float*)d_in[2];
    const float* b_in  = (const float*)d_in[3];
    const float* w1    = (const float*)d_in[4];
    const float* b1    = (const float*)d_in[5];
    const float* w2    = (const float*)d_in[6];
    const float* b2    = (const float*)d_in[7];
    const float* w_out = (const float*)d_in[8];
    const float* b_out = (const float*)d_in[9];

    float* out  = (float*)d_out;
    float* xout = out;                                // [N, 64]
    float* x    = out + (size_t)NNODES * OUTDIM;      // [N, 128] live x

    char* p = (char*)d_ws;
    auto alloc = [&](size_t bytes) {
        char* r = p;
        p += (bytes + 63) & ~(size_t)63;
        return r;
    };
    int* deg        = (int*)alloc(NNODES * 4);
    int* row_ptr    = (int*)alloc((NNODES + 1) * 4);
    int* cursor     = (int*)alloc(NNODES * 4);
    int* bsum       = (int*)alloc(256 * 4);
    int* bofs       = (int*)alloc(256 * 4);
    int* sorted_src = (int*)alloc(NEDGES * 4);
    float* normb    = (float*)alloc(NNODES * 4);
    unsigned short* wT   = (unsigned short*)alloc((size_t)663552 * 2);
    unsigned short* xcat = (unsigned short*)alloc((size_t)NPAD * 256 * 2);
    float* y        = (float*)alloc((size_t)NNODES * HDIM * 4);

    // ---- CSR + norm + weight prep ----
    hipMemsetAsync(deg, 0, NNODES * sizeof(int), stream);
    count_kernel<<<(NEDGES + 255) / 256, 256, 0, stream>>>(dst, deg);
    bsum_kernel<<<196, 256, 0, stream>>>(deg, bsum);
    bscan_kernel<<<1, 256, 0, stream>>>(bsum, bofs);
    emit_kernel<<<196, 256, 0, stream>>>(deg, bofs, row_ptr, cursor, normb);
    fill_kernel<<<(NEDGES + 255) / 256, 256, 0, stream>>>(src, dst, cursor, sorted_src);
    prep_w_kernel<<<864, 256, 0, stream>>>(w_in, w1, w2, w_out, wT);

    // input layer: split inputs, GEMM, gather (writes x fp32 + xcat)
    split_x_kernel<<<(NPAD * 64) / 256, 256, 0, stream>>>(inputs, normb, xcat);
    gemm_kernel<128><<<NPAD / 128, 256, 0, stream>>>(xcat, wT, y);
    gather_fin128<0, true><<<NNODES / 4, 256, 0, stream>>>(
        y, row_ptr, sorted_src, normb, b_in, nullptr, x, xcat);

    // 6 residual blocks
    for (int i = 0; i < 6; ++i) {
        // h-conv: gather writes xcat only (no fp32 h materialized)
        gemm_kernel<128><<<NPAD / 128, 256, 0, stream>>>(xcat, wT + (size_t)(1 + i) * 49152, y);
        gather_fin128<0, false><<<NNODES / 4, 256, 0, stream>>>(
            y, row_ptr, sorted_src, normb, b1 + i * HDIM, nullptr, nullptr, xcat);
        // x-conv: residual update, writes x fp32 + xcat
        gemm_kernel<128><<<NPAD / 128, 256, 0, stream>>>(xcat, wT + (size_t)(7 + i) * 49152, y);
        gather_fin128<1, true><<<NNODES / 4, 256, 0, stream>>>(
            y, row_ptr, sorted_src, normb, b2 + i * HDIM, x, x, xcat);
    }

    // output layer (H -> 64, identity): xcat already holds split(x*norm)
    gemm_kernel<64><<<NPAD / 128, 256, 0, stream>>>(xcat, wT + (size_t)13 * 49152, y);
    gather_fin64<<<NNODES / 4, 256, 0, stream>>>(
        y, row_ptr, sorted_src, normb, b_out, xout);
}

// Round 5
// 1034.140 us; speedup vs baseline: 18.3663x; 1.3381x over previous
//
#include <hip/hip_runtime.h>

#define NNODES 50000
#define NPAD   50048   // 391 * 128
#define NEDGES 800000
#define HDIM 128
#define OUTDIM 64

typedef short short8 __attribute__((ext_vector_type(8)));
typedef float f32x4 __attribute__((ext_vector_type(4)));
typedef _Float16 f16x2 __attribute__((ext_vector_type(2)));

__device__ __forceinline__ unsigned short f2bf(float f) {
    unsigned int u = __builtin_bit_cast(unsigned int, f);
    unsigned int r = (u + 0x7FFFu + ((u >> 16) & 1u)) >> 16;
    return (unsigned short)r;
}
__device__ __forceinline__ float bf2f(unsigned short b) {
    unsigned int u = ((unsigned int)b) << 16;
    return __builtin_bit_cast(float, u);
}

// ---------------- CSR build ----------------
__global__ void count_kernel(const int* __restrict__ dst, int* __restrict__ deg) {
    int e = blockIdx.x * 256 + threadIdx.x;
    if (e < NEDGES) atomicAdd(&deg[dst[e]], 1);
}

__global__ __launch_bounds__(256) void bsum_kernel(const int* __restrict__ deg,
                                                   int* __restrict__ bsum) {
    __shared__ int red[256];
    int i = blockIdx.x * 256 + threadIdx.x;
    red[threadIdx.x] = (i < NNODES) ? deg[i] : 0;
    __syncthreads();
    for (int off = 128; off; off >>= 1) {
        if (threadIdx.x < off) red[threadIdx.x] += red[threadIdx.x + off];
        __syncthreads();
    }
    if (threadIdx.x == 0) bsum[blockIdx.x] = red[0];
}

__global__ __launch_bounds__(256) void bscan_kernel(const int* __restrict__ bsum,
                                                    int* __restrict__ bofs) {
    __shared__ int s[256];
    int t = threadIdx.x;
    int v = (t < 196) ? bsum[t] : 0;
    s[t] = v;
    __syncthreads();
    for (int off = 1; off < 256; off <<= 1) {
        int u = (t >= off) ? s[t - off] : 0;
        __syncthreads();
        s[t] += u;
        __syncthreads();
    }
    if (t < 196) bofs[t] = s[t] - v;  // exclusive
}

__global__ __launch_bounds__(256) void emit_kernel(
    const int* __restrict__ deg, const int* __restrict__ bofs,
    int* __restrict__ row_ptr, int* __restrict__ cursor, float* __restrict__ norm) {
    __shared__ int s[256];
    int t = threadIdx.x;
    int i = blockIdx.x * 256 + t;
    int v = (i < NNODES) ? deg[i] : 0;
    s[t] = v;
    __syncthreads();
    for (int off = 1; off < 256; off <<= 1) {
        int u = (t >= off) ? s[t - off] : 0;
        __syncthreads();
        s[t] += u;
        __syncthreads();
    }
    int excl = s[t] - v + bofs[blockIdx.x];
    if (i < NNODES) {
        row_ptr[i] = excl;
        cursor[i] = excl;
        norm[i] = rsqrtf(1.0f + (float)v);
    }
    if (i == NNODES - 1) row_ptr[NNODES] = NEDGES;
}

__global__ void fill_kernel(const int* __restrict__ src, const int* __restrict__ dst,
                            int* __restrict__ cursor, int* __restrict__ sorted_src) {
    int e = blockIdx.x * 256 + threadIdx.x;
    if (e < NEDGES) {
        int pos = atomicAdd(&cursor[dst[e]], 1);
        sorted_src[pos] = src[e];
    }
}

// ---------------- weight prep (bf16 hi/lo split, transposed) ----------------
__global__ __launch_bounds__(256) void prep_w_kernel(
    const float* __restrict__ w_in, const float* __restrict__ w1,
    const float* __restrict__ w2, const float* __restrict__ w_out,
    unsigned short* __restrict__ wT) {
    int idx = blockIdx.x * 256 + threadIdx.x;  // total 221184 = 864*256
    const float* W;
    unsigned short* o;
    int Nc, e;
    if (idx < 16384) {
        W = w_in; o = wT; Nc = 128; e = idx;
    } else if (idx < 16384 + 98304) {
        int j = idx - 16384; int m = j >> 14; e = j & 16383;
        W = w1 + ((size_t)m << 14); o = wT + (size_t)(1 + m) * 49152; Nc = 128;
    } else if (idx < 16384 + 196608) {
        int j = idx - 16384 - 98304; int m = j >> 14; e = j & 16383;
        W = w2 + ((size_t)m << 14); o = wT + (size_t)(7 + m) * 49152; Nc = 128;
    } else {
        e = idx - 212992;
        W = w_out; o = wT + (size_t)13 * 49152; Nc = 64;
    }
    int k = (Nc == 128) ? (e >> 7) : (e >> 6);
    int n = (Nc == 128) ? (e & 127) : (e & 63);
    float v = W[e];
    unsigned short h = f2bf(v);
    unsigned short l = f2bf(v - bf2f(h));
    o[(size_t)n * 384 + k] = h;
    o[(size_t)n * 384 + 128 + k] = h;
    o[(size_t)n * 384 + 256 + k] = l;
}

// ---------------- x split (input layer only) ----------------
__global__ __launch_bounds__(256) void split_x_kernel(
    const float* __restrict__ x, const float* __restrict__ norm,
    unsigned short* __restrict__ xcat) {
    int gid = blockIdx.x * 256 + threadIdx.x;
    int row = gid >> 6;
    int kk = (gid & 63) * 2;
    float2 v = {0.f, 0.f};
    float nm = 0.f;
    if (row < NNODES) {
        v = *(const float2*)(x + (size_t)row * 128 + kk);
        nm = norm[row];
    }
    float a0 = v.x * nm, a1 = v.y * nm;
    unsigned short h0 = f2bf(a0), h1 = f2bf(a1);
    unsigned short l0 = f2bf(a0 - bf2f(h0)), l1 = f2bf(a1 - bf2f(h1));
    unsigned int hi = (unsigned int)h0 | ((unsigned int)h1 << 16);
    unsigned int lo = (unsigned int)l0 | ((unsigned int)l1 << 16);
    *(unsigned int*)(xcat + (size_t)row * 256 + kk) = hi;
    *(unsigned int*)(xcat + (size_t)row * 256 + 128 + kk) = lo;
}

// ---------------- MFMA GEMM: y16[M,NCOLS] = xcat(K=384 remap) @ WT^T, fp16 out
template <int NCOLS>
__global__ __launch_bounds__(256) void gemm_kernel(
    const unsigned short* __restrict__ xcat, const unsigned short* __restrict__ wT,
    _Float16* __restrict__ y) {
    constexpr int MT = (NCOLS == 128) ? 4 : 2;
    __shared__ unsigned short Alds[128 * 32];
    __shared__ unsigned short Blds[NCOLS * 32];
    const int t = threadIdx.x;
    const int wave = t >> 6, lane = t & 63, quad = lane >> 4, l16 = lane & 15;
    const int row0 = blockIdx.x * 128;
    const int wm = (NCOLS == 128) ? (wave >> 1) * 64 : wave * 32;
    const int wn = (NCOLS == 128) ? (wave & 1) * 64 : 0;

    f32x4 acc[MT][4];
#pragma unroll
    for (int mt = 0; mt < MT; ++mt)
#pragma unroll
        for (int nt = 0; nt < 4; ++nt) acc[mt][nt] = (f32x4){0.f, 0.f, 0.f, 0.f};

    for (int ks = 0; ks < 12; ++ks) {
        const int k0 = ks * 32;
        const int keff = (k0 >= 256) ? (k0 - 256) : k0;  // A slot2 re-reads hi
        __syncthreads();
#pragma unroll
        for (int i = 0; i < 2; ++i) {
            int c = i * 256 + t;
            int m = c >> 2, q = c & 3;
            const unsigned short* gp = xcat + (size_t)(row0 + m) * 256 + keff + q * 8;
            unsigned short* lp = Alds + (size_t)c * 8;
            __builtin_amdgcn_global_load_lds(
                (const __attribute__((address_space(1))) void*)gp,
                (__attribute__((address_space(3))) void*)lp, 16, 0, 0);
        }
#pragma unroll
        for (int i = 0; i < (NCOLS * 4) / 256; ++i) {
            int c = i * 256 + t;
            int n = c >> 2, q = c & 3;
            const unsigned short* gp = wT + (size_t)n * 384 + k0 + q * 8;
            unsigned short* lp = Blds + (size_t)c * 8;
            __builtin_amdgcn_global_load_lds(
                (const __attribute__((address_space(1))) void*)gp,
                (__attribute__((address_space(3))) void*)lp, 16, 0, 0);
        }
        __syncthreads();

        short8 a[MT], b[4];
#pragma unroll
        for (int mt = 0; mt < MT; ++mt)
            a[mt] = *(const short8*)(Alds + (size_t)(wm + mt * 16 + l16) * 32 + quad * 8);
#pragma unroll
        for (int nt = 0; nt < 4; ++nt)
            b[nt] = *(const short8*)(Blds + (size_t)(wn + nt * 16 + l16) * 32 + quad * 8);
#pragma unroll
        for (int mt = 0; mt < MT; ++mt)
#pragma unroll
            for (int nt = 0; nt < 4; ++nt)
                acc[mt][nt] = __builtin_amdgcn_mfma_f32_16x16x32_bf16(
                    a[mt], b[nt], acc[mt][nt], 0, 0, 0);
    }

#pragma unroll
    for (int mt = 0; mt < MT; ++mt) {
        int mbase = row0 + wm + mt * 16 + quad * 4;
#pragma unroll
        for (int nt = 0; nt < 4; ++nt) {
            int col = wn + nt * 16 + l16;
#pragma unroll
            for (int r = 0; r < 4; ++r) {
                int row = mbase + r;
                if (row < NNODES) y[(size_t)row * NCOLS + col] = (_Float16)acc[mt][nt][r];
            }
        }
    }
}

// ---------------- fused gather + finalize + bf16 split (F=128, fp16 y) ------
// Full wave per node; lane owns cols (2*lane, 2*lane+1). Row = 256 B = 64
// lanes x half2. 8-deep unroll -> 2 KB row loads in flight per wave. No
// cross-lane reduction needed.
template <int MODE, bool WOUT>  // MODE 0: plain leaky; 1: residual
__global__ __launch_bounds__(256) void gather_fin128(
    const _Float16* __restrict__ y, const int* __restrict__ row_ptr,
    const int* __restrict__ sorted_src, const float* __restrict__ norm,
    const float* __restrict__ bias, const float* __restrict__ xres,
    float* __restrict__ out, unsigned short* __restrict__ xcat) {
    const int wave = threadIdx.x >> 6;
    const int lane = threadIdx.x & 63;
    const int n = blockIdx.x * 4 + wave;
    const int beg = row_ptr[n];
    const int end = row_ptr[n + 1];

    float2 a0 = {0.f, 0.f}, a1 = a0, a2 = a0, a3 = a0, a4 = a0, a5 = a0, a6 = a0, a7 = a0;
    int i = beg;
    for (; i + 7 < end; i += 8) {
        int s0 = sorted_src[i], s1 = sorted_src[i + 1];
        int s2 = sorted_src[i + 2], s3 = sorted_src[i + 3];
        int s4 = sorted_src[i + 4], s5 = sorted_src[i + 5];
        int s6 = sorted_src[i + 6], s7 = sorted_src[i + 7];
        f16x2 h0 = *(const f16x2*)(y + (size_t)s0 * 128 + lane * 2);
        f16x2 h1 = *(const f16x2*)(y + (size_t)s1 * 128 + lane * 2);
        f16x2 h2 = *(const f16x2*)(y + (size_t)s2 * 128 + lane * 2);
        f16x2 h3 = *(const f16x2*)(y + (size_t)s3 * 128 + lane * 2);
        f16x2 h4 = *(const f16x2*)(y + (size_t)s4 * 128 + lane * 2);
        f16x2 h5 = *(const f16x2*)(y + (size_t)s5 * 128 + lane * 2);
        f16x2 h6 = *(const f16x2*)(y + (size_t)s6 * 128 + lane * 2);
        f16x2 h7 = *(const f16x2*)(y + (size_t)s7 * 128 + lane * 2);
        a0.x += (float)h0.x; a0.y += (float)h0.y;
        a1.x += (float)h1.x; a1.y += (float)h1.y;
        a2.x += (float)h2.x; a2.y += (float)h2.y;
        a3.x += (float)h3.x; a3.y += (float)h3.y;
        a4.x += (float)h4.x; a4.y += (float)h4.y;
        a5.x += (float)h5.x; a5.y += (float)h5.y;
        a6.x += (float)h6.x; a6.y += (float)h6.y;
        a7.x += (float)h7.x; a7.y += (float)h7.y;
    }
    for (; i < end; ++i) {
        int s = sorted_src[i];
        f16x2 h = *(const f16x2*)(y + (size_t)s * 128 + lane * 2);
        a0.x += (float)h.x; a0.y += (float)h.y;
    }
    a0.x += a1.x; a0.y += a1.y;
    a2.x += a3.x; a2.y += a3.y;
    a4.x += a5.x; a4.y += a5.y;
    a6.x += a7.x; a6.y += a7.y;
    a0.x += a2.x; a0.y += a2.y;
    a4.x += a6.x; a4.y += a6.y;
    a0.x += a4.x; a0.y += a4.y;

    const f16x2 sh = *(const f16x2*)(y + (size_t)n * 128 + lane * 2);
    const float2 bi = *(const float2*)(bias + lane * 2);
    const float nm = norm[n];
    float v0 = (a0.x + (float)sh.x) * nm + bi.x;
    float v1 = (a0.y + (float)sh.y) * nm + bi.y;
    v0 = v0 >= 0.f ? v0 : 0.01f * v0;
    v1 = v1 >= 0.f ? v1 : 0.01f * v1;
    if (MODE == 1) {
        const float2 xr = *(const float2*)(xres + (size_t)n * 128 + lane * 2);
        v0 = (xr.x + v0) * 0.5f;
        v1 = (xr.y + v1) * 0.5f;
    }
    if (WOUT) {
        float2 o = {v0, v1};
        *(float2*)(out + (size_t)n * 128 + lane * 2) = o;
    }
    // xcat = hi/lo split of v*norm
    float s0 = v0 * nm, s1 = v1 * nm;
    unsigned short h0 = f2bf(s0), h1 = f2bf(s1);
    unsigned short l0 = f2bf(s0 - bf2f(h0)), l1 = f2bf(s1 - bf2f(h1));
    *(unsigned int*)(xcat + (size_t)n * 256 + lane * 2) =
        (unsigned int)h0 | ((unsigned int)h1 << 16);
    *(unsigned int*)(xcat + (size_t)n * 256 + 128 + lane * 2) =
        (unsigned int)l0 | ((unsigned int)l1 << 16);
}

// ---------------- final gather (F=64, identity, fp16 y) ----------------
__global__ __launch_bounds__(256) void gather_fin64(
    const _Float16* __restrict__ y, const int* __restrict__ row_ptr,
    const int* __restrict__ sorted_src, const float* __restrict__ norm,
    const float* __restrict__ bias, float* __restrict__ out) {
    const int wave = threadIdx.x >> 6;
    const int lane = threadIdx.x & 63;
    const int n = blockIdx.x * 4 + wave;
    const int beg = row_ptr[n];
    const int end = row_ptr[n + 1];
    float a0 = 0.f, a1 = 0.f, a2 = 0.f, a3 = 0.f;
    int i = beg;
    for (; i + 3 < end; i += 4) {
        int s0 = sorted_src[i], s1 = sorted_src[i + 1];
        int s2 = sorted_src[i + 2], s3 = sorted_src[i + 3];
        a0 += (float)y[(size_t)s0 * 64 + lane];
        a1 += (float)y[(size_t)s1 * 64 + lane];
        a2 += (float)y[(size_t)s2 * 64 + lane];
        a3 += (float)y[(size_t)s3 * 64 + lane];
    }
    for (; i < end; ++i) a0 += (float)y[(size_t)sorted_src[i] * 64 + lane];
    a0 += a1; a2 += a3; a0 += a2;
    float self = (float)y[(size_t)n * 64 + lane];
    out[(size_t)n * 64 + lane] = (a0 + self) * norm[n] + bias[lane];
}

extern "C" void kernel_launch(void* const* d_in, const int* in_sizes, int n_in,
                              void* d_out, int out_size, void* d_ws, size_t ws_size,
                              hipStream_t stream) {
    const float* inputs = (const float*)d_in[0];
    const int* edges = (const int*)d_in[1];
    const int* src = edges;
    const int* dst = edges + NEDGES;
    const float* w_in  = (const float*)d_in[2];
    const float* b_in  = (const float*)d_in[3];
    const float* w1    = (const float*)d_in[4];
    const float* b1    = (const float*)d_in[5];
    const float* w2    = (const float*)d_in[6];
    const float* b2    = (const float*)d_in[7];
    const float* w_out = (const float*)d_in[8];
    const float* b_out = (const float*)d_in[9];

    float* out  = (float*)d_out;
    float* xout = out;                                // [N, 64]
    float* x    = out + (size_t)NNODES * OUTDIM;      // [N, 128] live x

    char* p = (char*)d_ws;
    auto alloc = [&](size_t bytes) {
        char* r = p;
        p += (bytes + 63) & ~(size_t)63;
        return r;
    };
    int* deg        = (int*)alloc(NNODES * 4);
    int* row_ptr    = (int*)alloc((NNODES + 1) * 4);
    int* cursor     = (int*)alloc(NNODES * 4);
    int* bsum       = (int*)alloc(256 * 4);
    int* bofs       = (int*)alloc(256 * 4);
    int* sorted_src = (int*)alloc(NEDGES * 4);
    float* normb    = (float*)alloc(NNODES * 4);
    unsigned short* wT   = (unsigned short*)alloc((size_t)663552 * 2);
    unsigned short* xcat = (unsigned short*)alloc((size_t)NPAD * 256 * 2);
    _Float16* y     = (_Float16*)alloc((size_t)NNODES * HDIM * 2);

    // ---- CSR + norm + weight prep ----
    hipMemsetAsync(deg, 0, NNODES * sizeof(int), stream);
    count_kernel<<<(NEDGES + 255) / 256, 256, 0, stream>>>(dst, deg);
    bsum_kernel<<<196, 256, 0, stream>>>(deg, bsum);
    bscan_kernel<<<1, 256, 0, stream>>>(bsum, bofs);
    emit_kernel<<<196, 256, 0, stream>>>(deg, bofs, row_ptr, cursor, normb);
    fill_kernel<<<(NEDGES + 255) / 256, 256, 0, stream>>>(src, dst, cursor, sorted_src);
    prep_w_kernel<<<864, 256, 0, stream>>>(w_in, w1, w2, w_out, wT);

    // input layer: split inputs, GEMM, gather (writes x fp32 + xcat)
    split_x_kernel<<<(NPAD * 64) / 256, 256, 0, stream>>>(inputs, normb, xcat);
    gemm_kernel<128><<<NPAD / 128, 256, 0, stream>>>(xcat, wT, y);
    gather_fin128<0, true><<<NNODES / 4, 256, 0, stream>>>(
        y, row_ptr, sorted_src, normb, b_in, nullptr, x, xcat);

    // 6 residual blocks
    for (int i = 0; i < 6; ++i) {
        gemm_kernel<128><<<NPAD / 128, 256, 0, stream>>>(xcat, wT + (size_t)(1 + i) * 49152, y);
        gather_fin128<0, false><<<NNODES / 4, 256, 0, stream>>>(
            y, row_ptr, sorted_src, normb, b1 + i * HDIM, nullptr, nullptr, xcat);
        gemm_kernel<128><<<NPAD / 128, 256, 0, stream>>>(xcat, wT + (size_t)(7 + i) * 49152, y);
        gather_fin128<1, true><<<NNODES / 4, 256, 0, stream>>>(
            y, row_ptr, sorted_src, normb, b2 + i * HDIM, x, x, xcat);
    }

    // output layer (H -> 64, identity): xcat already holds split(x*norm)
    gemm_kernel<64><<<NPAD / 128, 256, 0, stream>>>(xcat, wT + (size_t)13 * 49152, y);
    gather_fin64<<<NNODES / 4, 256, 0, stream>>>(
        y, row_ptr, sorted_src, normb, b_out, xout);
}

// Round 6
// 1026.671 us; speedup vs baseline: 18.4999x; 1.0073x over previous
//
#include <hip/hip_runtime.h>

#define NNODES 50000
#define NPAD   50048   // 391 * 128
#define NEDGES 800000
#define HDIM 128
#define OUTDIM 64

typedef short short8 __attribute__((ext_vector_type(8)));
typedef float f32x4 __attribute__((ext_vector_type(4)));
typedef _Float16 f16x2 __attribute__((ext_vector_type(2)));

__device__ __forceinline__ unsigned short f2bf(float f) {
    unsigned int u = __builtin_bit_cast(unsigned int, f);
    unsigned int r = (u + 0x7FFFu + ((u >> 16) & 1u)) >> 16;
    return (unsigned short)r;
}
__device__ __forceinline__ float bf2f(unsigned short b) {
    unsigned int u = ((unsigned int)b) << 16;
    return __builtin_bit_cast(float, u);
}

// ---------------- CSR build ----------------
__global__ void count_kernel(const int* __restrict__ dst, int* __restrict__ deg) {
    int e = blockIdx.x * 256 + threadIdx.x;
    if (e < NEDGES) atomicAdd(&deg[dst[e]], 1);
}

__global__ __launch_bounds__(256) void bsum_kernel(const int* __restrict__ deg,
                                                   int* __restrict__ bsum) {
    __shared__ int red[256];
    int i = blockIdx.x * 256 + threadIdx.x;
    red[threadIdx.x] = (i < NNODES) ? deg[i] : 0;
    __syncthreads();
    for (int off = 128; off; off >>= 1) {
        if (threadIdx.x < off) red[threadIdx.x] += red[threadIdx.x + off];
        __syncthreads();
    }
    if (threadIdx.x == 0) bsum[blockIdx.x] = red[0];
}

__global__ __launch_bounds__(256) void bscan_kernel(const int* __restrict__ bsum,
                                                    int* __restrict__ bofs) {
    __shared__ int s[256];
    int t = threadIdx.x;
    int v = (t < 196) ? bsum[t] : 0;
    s[t] = v;
    __syncthreads();
    for (int off = 1; off < 256; off <<= 1) {
        int u = (t >= off) ? s[t - off] : 0;
        __syncthreads();
        s[t] += u;
        __syncthreads();
    }
    if (t < 196) bofs[t] = s[t] - v;  // exclusive
}

__global__ __launch_bounds__(256) void emit_kernel(
    const int* __restrict__ deg, const int* __restrict__ bofs,
    int* __restrict__ row_ptr, int* __restrict__ cursor, float* __restrict__ norm) {
    __shared__ int s[256];
    int t = threadIdx.x;
    int i = blockIdx.x * 256 + t;
    int v = (i < NNODES) ? deg[i] : 0;
    s[t] = v;
    __syncthreads();
    for (int off = 1; off < 256; off <<= 1) {
        int u = (t >= off) ? s[t - off] : 0;
        __syncthreads();
        s[t] += u;
        __syncthreads();
    }
    int excl = s[t] - v + bofs[blockIdx.x];
    if (i < NNODES) {
        row_ptr[i] = excl;
        cursor[i] = excl;
        norm[i] = rsqrtf(1.0f + (float)v);
    }
    if (i == NNODES - 1) row_ptr[NNODES] = NEDGES;
}

__global__ void fill_kernel(const int* __restrict__ src, const int* __restrict__ dst,
                            int* __restrict__ cursor, int* __restrict__ sorted_src) {
    int e = blockIdx.x * 256 + threadIdx.x;
    if (e < NEDGES) {
        int pos = atomicAdd(&cursor[dst[e]], 1);
        sorted_src[pos] = src[e];
    }
}

// ---------------- weight prep: W[K][Nc] fp32 -> wT[n][0:128]=hi, [128:256]=lo
// slot stride 32768 shorts (Nc=128); w_out at 13*32768 (64 rows).
__global__ __launch_bounds__(256) void prep_w_kernel(
    const float* __restrict__ w_in, const float* __restrict__ w1,
    const float* __restrict__ w2, const float* __restrict__ w_out,
    unsigned short* __restrict__ wT) {
    int idx = blockIdx.x * 256 + threadIdx.x;  // total 221184 = 864*256
    const float* W;
    unsigned short* o;
    int Nc, e;
    if (idx < 16384) {
        W = w_in; o = wT; Nc = 128; e = idx;
    } else if (idx < 16384 + 98304) {
        int j = idx - 16384; int m = j >> 14; e = j & 16383;
        W = w1 + ((size_t)m << 14); o = wT + (size_t)(1 + m) * 32768; Nc = 128;
    } else if (idx < 16384 + 196608) {
        int j = idx - 16384 - 98304; int m = j >> 14; e = j & 16383;
        W = w2 + ((size_t)m << 14); o = wT + (size_t)(7 + m) * 32768; Nc = 128;
    } else {
        e = idx - 212992;
        W = w_out; o = wT + (size_t)13 * 32768; Nc = 64;
    }
    int k = (Nc == 128) ? (e >> 7) : (e >> 6);
    int n = (Nc == 128) ? (e & 127) : (e & 63);
    float v = W[e];
    unsigned short h = f2bf(v);
    unsigned short l = f2bf(v - bf2f(h));
    o[(size_t)n * 256 + k] = h;
    o[(size_t)n * 256 + 128 + k] = l;
}

// ---------------- x split (input layer only): xc = split(inputs), no norm ----
__global__ __launch_bounds__(256) void split_x_kernel(
    const float* __restrict__ x, unsigned short* __restrict__ xc) {
    int gid = blockIdx.x * 256 + threadIdx.x;
    int row = gid >> 6;
    int kk = (gid & 63) * 2;
    float2 v = {0.f, 0.f};
    if (row < NNODES) v = *(const float2*)(x + (size_t)row * 128 + kk);
    unsigned short h0 = f2bf(v.x), h1 = f2bf(v.y);
    unsigned short l0 = f2bf(v.x - bf2f(h0)), l1 = f2bf(v.y - bf2f(h1));
    *(unsigned int*)(xc + (size_t)row * 256 + kk) =
        (unsigned int)h0 | ((unsigned int)h1 << 16);
    *(unsigned int*)(xc + (size_t)row * 256 + 128 + kk) =
        (unsigned int)l0 | ((unsigned int)l1 << 16);
}

// ---------------- MFMA GEMM: y16 = ((hi+lo)@W) * norm[row], fp16 out --------
// xc[row][256]: hi|lo. wT[n][256]: Whi|Wlo. Physical K=256, 8 chunks of 32.
// A-hi chunks (ks<4) pair with BOTH Whi and Wlo; A-lo chunks pair with Whi.
template <int NCOLS>
__global__ __launch_bounds__(256) void gemm_kernel(
    const unsigned short* __restrict__ xc, const unsigned short* __restrict__ wT,
    const float* __restrict__ norm, _Float16* __restrict__ y) {
    constexpr int MT = (NCOLS == 128) ? 4 : 2;
    __shared__ unsigned short Alds[128 * 32];
    __shared__ unsigned short B1lds[NCOLS * 32];
    __shared__ unsigned short B2lds[NCOLS * 32];
    const int t = threadIdx.x;
    const int wave = t >> 6, lane = t & 63, quad = lane >> 4, l16 = lane & 15;
    const int row0 = blockIdx.x * 128;
    const int wm = (NCOLS == 128) ? (wave >> 1) * 64 : wave * 32;
    const int wn = (NCOLS == 128) ? (wave & 1) * 64 : 0;

    f32x4 acc[MT][4];
#pragma unroll
    for (int mt = 0; mt < MT; ++mt)
#pragma unroll
        for (int nt = 0; nt < 4; ++nt) acc[mt][nt] = (f32x4){0.f, 0.f, 0.f, 0.f};

    for (int ks = 0; ks < 8; ++ks) {
        const int k0 = ks * 32;
        const int kb = (ks < 4) ? k0 : (k0 - 128);  // Whi chunk cols
        __syncthreads();
#pragma unroll
        for (int i = 0; i < 2; ++i) {  // A: 512 x 16B chunks
            int c = i * 256 + t;
            int m = c >> 2, q = c & 3;
            const unsigned short* gp = xc + (size_t)(row0 + m) * 256 + k0 + q * 8;
            unsigned short* lp = Alds + (size_t)c * 8;
            __builtin_amdgcn_global_load_lds(
                (const __attribute__((address_space(1))) void*)gp,
                (__attribute__((address_space(3))) void*)lp, 16, 0, 0);
        }
#pragma unroll
        for (int i = 0; i < (NCOLS * 4) / 256; ++i) {  // B1 = Whi chunk
            int c = i * 256 + t;
            int n = c >> 2, q = c & 3;
            const unsigned short* gp = wT + (size_t)n * 256 + kb + q * 8;
            unsigned short* lp = B1lds + (size_t)c * 8;
            __builtin_amdgcn_global_load_lds(
                (const __attribute__((address_space(1))) void*)gp,
                (__attribute__((address_space(3))) void*)lp, 16, 0, 0);
        }
        if (ks < 4) {
#pragma unroll
            for (int i = 0; i < (NCOLS * 4) / 256; ++i) {  // B2 = Wlo chunk
                int c = i * 256 + t;
                int n = c >> 2, q = c & 3;
                const unsigned short* gp = wT + (size_t)n * 256 + 128 + k0 + q * 8;
                unsigned short* lp = B2lds + (size_t)c * 8;
                __builtin_amdgcn_global_load_lds(
                    (const __attribute__((address_space(1))) void*)gp,
                    (__attribute__((address_space(3))) void*)lp, 16, 0, 0);
            }
        }
        __syncthreads();

        short8 a[MT], b1[4];
#pragma unroll
        for (int mt = 0; mt < MT; ++mt)
            a[mt] = *(const short8*)(Alds + (size_t)(wm + mt * 16 + l16) * 32 + quad * 8);
#pragma unroll
        for (int nt = 0; nt < 4; ++nt)
            b1[nt] = *(const short8*)(B1lds + (size_t)(wn + nt * 16 + l16) * 32 + quad * 8);
#pragma unroll
        for (int mt = 0; mt < MT; ++mt)
#pragma unroll
            for (int nt = 0; nt < 4; ++nt)
                acc[mt][nt] = __builtin_amdgcn_mfma_f32_16x16x32_bf16(
                    a[mt], b1[nt], acc[mt][nt], 0, 0, 0);
        if (ks < 4) {
            short8 b2[4];
#pragma unroll
            for (int nt = 0; nt < 4; ++nt)
                b2[nt] = *(const short8*)(B2lds + (size_t)(wn + nt * 16 + l16) * 32 + quad * 8);
#pragma unroll
            for (int mt = 0; mt < MT; ++mt)
#pragma unroll
                for (int nt = 0; nt < 4; ++nt)
                    acc[mt][nt] = __builtin_amdgcn_mfma_f32_16x16x32_bf16(
                        a[mt], b2[nt], acc[mt][nt], 0, 0, 0);
        }
    }

#pragma unroll
    for (int mt = 0; mt < MT; ++mt) {
        int mbase = row0 + wm + mt * 16 + quad * 4;
#pragma unroll
        for (int r = 0; r < 4; ++r) {
            int row = mbase + r;
            if (row < NNODES) {
                float nm = norm[row];
#pragma unroll
                for (int nt = 0; nt < 4; ++nt) {
                    int col = wn + nt * 16 + l16;
                    y[(size_t)row * NCOLS + col] = (_Float16)(acc[mt][nt][r] * nm);
                }
            }
        }
    }
}

// ---------------- fused gather + finalize + hi/lo split (F=128, fp16 y) -----
// Full wave per node; lane owns cols (2*lane, 2*lane+1). 8-deep unroll.
// v = act((sum + self)*norm + b) [+ residual from xcres hi/lo]; writes
// xcout = split(v) (unscaled); fp32 out only if WOUT.
template <int MODE, bool WOUT>  // MODE 0: plain leaky; 1: residual
__global__ __launch_bounds__(256) void gather_fin128(
    const _Float16* __restrict__ y, const int* __restrict__ row_ptr,
    const int* __restrict__ sorted_src, const float* __restrict__ norm,
    const float* __restrict__ bias, const unsigned short* __restrict__ xcres,
    float* __restrict__ out, unsigned short* __restrict__ xcout) {
    const int wave = threadIdx.x >> 6;
    const int lane = threadIdx.x & 63;
    const int n = blockIdx.x * 4 + wave;
    const int beg = row_ptr[n];
    const int end = row_ptr[n + 1];

    float2 a0 = {0.f, 0.f}, a1 = a0, a2 = a0, a3 = a0, a4 = a0, a5 = a0, a6 = a0, a7 = a0;
    int i = beg;
    for (; i + 7 < end; i += 8) {
        int s0 = sorted_src[i], s1 = sorted_src[i + 1];
        int s2 = sorted_src[i + 2], s3 = sorted_src[i + 3];
        int s4 = sorted_src[i + 4], s5 = sorted_src[i + 5];
        int s6 = sorted_src[i + 6], s7 = sorted_src[i + 7];
        f16x2 h0 = *(const f16x2*)(y + (size_t)s0 * 128 + lane * 2);
        f16x2 h1 = *(const f16x2*)(y + (size_t)s1 * 128 + lane * 2);
        f16x2 h2 = *(const f16x2*)(y + (size_t)s2 * 128 + lane * 2);
        f16x2 h3 = *(const f16x2*)(y + (size_t)s3 * 128 + lane * 2);
        f16x2 h4 = *(const f16x2*)(y + (size_t)s4 * 128 + lane * 2);
        f16x2 h5 = *(const f16x2*)(y + (size_t)s5 * 128 + lane * 2);
        f16x2 h6 = *(const f16x2*)(y + (size_t)s6 * 128 + lane * 2);
        f16x2 h7 = *(const f16x2*)(y + (size_t)s7 * 128 + lane * 2);
        a0.x += (float)h0.x; a0.y += (float)h0.y;
        a1.x += (float)h1.x; a1.y += (float)h1.y;
        a2.x += (float)h2.x; a2.y += (float)h2.y;
        a3.x += (float)h3.x; a3.y += (float)h3.y;
        a4.x += (float)h4.x; a4.y += (float)h4.y;
        a5.x += (float)h5.x; a5.y += (float)h5.y;
        a6.x += (float)h6.x; a6.y += (float)h6.y;
        a7.x += (float)h7.x; a7.y += (float)h7.y;
    }
    for (; i < end; ++i) {
        int s = sorted_src[i];
        f16x2 h = *(const f16x2*)(y + (size_t)s * 128 + lane * 2);
        a0.x += (float)h.x; a0.y += (float)h.y;
    }
    a0.x += a1.x; a0.y += a1.y;
    a2.x += a3.x; a2.y += a3.y;
    a4.x += a5.x; a4.y += a5.y;
    a6.x += a7.x; a6.y += a7.y;
    a0.x += a2.x; a0.y += a2.y;
    a4.x += a6.x; a4.y += a6.y;
    a0.x += a4.x; a0.y += a4.y;

    const f16x2 sh = *(const f16x2*)(y + (size_t)n * 128 + lane * 2);
    const float2 bi = *(const float2*)(bias + lane * 2);
    const float nm = norm[n];
    float v0 = (a0.x + (float)sh.x) * nm + bi.x;
    float v1 = (a0.y + (float)sh.y) * nm + bi.y;
    v0 = v0 >= 0.f ? v0 : 0.01f * v0;
    v1 = v1 >= 0.f ? v1 : 0.01f * v1;
    if (MODE == 1) {
        unsigned int hw = *(const unsigned int*)(xcres + (size_t)n * 256 + lane * 2);
        unsigned int lw = *(const unsigned int*)(xcres + (size_t)n * 256 + 128 + lane * 2);
        float xr0 = bf2f((unsigned short)hw) + bf2f((unsigned short)lw);
        float xr1 = bf2f((unsigned short)(hw >> 16)) + bf2f((unsigned short)(lw >> 16));
        v0 = (xr0 + v0) * 0.5f;
        v1 = (xr1 + v1) * 0.5f;
    }
    if (WOUT) {
        float2 o = {v0, v1};
        *(float2*)(out + (size_t)n * 128 + lane * 2) = o;
    }
    unsigned short h0 = f2bf(v0), h1 = f2bf(v1);
    unsigned short l0 = f2bf(v0 - bf2f(h0)), l1 = f2bf(v1 - bf2f(h1));
    *(unsigned int*)(xcout + (size_t)n * 256 + lane * 2) =
        (unsigned int)h0 | ((unsigned int)h1 << 16);
    *(unsigned int*)(xcout + (size_t)n * 256 + 128 + lane * 2) =
        (unsigned int)l0 | ((unsigned int)l1 << 16);
}

// ---------------- final gather (F=64, identity, fp16 y) ----------------
__global__ __launch_bounds__(256) void gather_fin64(
    const _Float16* __restrict__ y, const int* __restrict__ row_ptr,
    const int* __restrict__ sorted_src, const float* __restrict__ norm,
    const float* __restrict__ bias, float* __restrict__ out) {
    const int wave = threadIdx.x >> 6;
    const int lane = threadIdx.x & 63;
    const int n = blockIdx.x * 4 + wave;
    const int beg = row_ptr[n];
    const int end = row_ptr[n + 1];
    float a0 = 0.f, a1 = 0.f, a2 = 0.f, a3 = 0.f;
    int i = beg;
    for (; i + 3 < end; i += 4) {
        int s0 = sorted_src[i], s1 = sorted_src[i + 1];
        int s2 = sorted_src[i + 2], s3 = sorted_src[i + 3];
        a0 += (float)y[(size_t)s0 * 64 + lane];
        a1 += (float)y[(size_t)s1 * 64 + lane];
        a2 += (float)y[(size_t)s2 * 64 + lane];
        a3 += (float)y[(size_t)s3 * 64 + lane];
    }
    for (; i < end; ++i) a0 += (float)y[(size_t)sorted_src[i] * 64 + lane];
    a0 += a1; a2 += a3; a0 += a2;
    float self = (float)y[(size_t)n * 64 + lane];
    out[(size_t)n * 64 + lane] = (a0 + self) * norm[n] + bias[lane];
}

extern "C" void kernel_launch(void* const* d_in, const int* in_sizes, int n_in,
                              void* d_out, int out_size, void* d_ws, size_t ws_size,
                              hipStream_t stream) {
    const float* inputs = (const float*)d_in[0];
    const int* edges = (const int*)d_in[1];
    const int* src = edges;
    const int* dst = edges + NEDGES;
    const float* w_in  = (const float*)d_in[2];
    const float* b_in  = (const float*)d_in[3];
    const float* w1    = (const float*)d_in[4];
    const float* b1    = (const float*)d_in[5];
    const float* w2    = (const float*)d_in[6];
    const float* b2    = (const float*)d_in[7];
    const float* w_out = (const float*)d_in[8];
    const float* b_out = (const float*)d_in[9];

    float* out  = (float*)d_out;
    float* xout = out;                                // [N, 64]
    float* x    = out + (size_t)NNODES * OUTDIM;      // [N, 128] fp32 x (final only)

    char* p = (char*)d_ws;
    auto alloc = [&](size_t bytes) {
        char* r = p;
        p += (bytes + 63) & ~(size_t)63;
        return r;
    };
    int* deg        = (int*)alloc(NNODES * 4);
    int* row_ptr    = (int*)alloc((NNODES + 1) * 4);
    int* cursor     = (int*)alloc(NNODES * 4);
    int* bsum       = (int*)alloc(256 * 4);
    int* bofs       = (int*)alloc(256 * 4);
    int* sorted_src = (int*)alloc(NEDGES * 4);
    float* normb    = (float*)alloc(NNODES * 4);
    unsigned short* wT   = (unsigned short*)alloc((size_t)442368 * 2);  // 13*32768+16384
    unsigned short* xc_x = (unsigned short*)alloc((size_t)NPAD * 256 * 2);
    unsigned short* xc_h = (unsigned short*)alloc((size_t)NPAD * 256 * 2);
    _Float16* y     = (_Float16*)alloc((size_t)NNODES * HDIM * 2);

    // ---- CSR + norm + weight prep ----
    hipMemsetAsync(deg, 0, NNODES * sizeof(int), stream);
    count_kernel<<<(NEDGES + 255) / 256, 256, 0, stream>>>(dst, deg);
    bsum_kernel<<<196, 256, 0, stream>>>(deg, bsum);
    bscan_kernel<<<1, 256, 0, stream>>>(bsum, bofs);
    emit_kernel<<<196, 256, 0, stream>>>(deg, bofs, row_ptr, cursor, normb);
    fill_kernel<<<(NEDGES + 255) / 256, 256, 0, stream>>>(src, dst, cursor, sorted_src);
    prep_w_kernel<<<864, 256, 0, stream>>>(w_in, w1, w2, w_out, wT);

    // input layer: xc_h = split(inputs); y = (inputs@W_in)*norm; gather -> xc_x
    split_x_kernel<<<(NPAD * 64) / 256, 256, 0, stream>>>(inputs, xc_h);
    gemm_kernel<128><<<NPAD / 128, 256, 0, stream>>>(xc_h, wT, normb, y);
    gather_fin128<0, false><<<NNODES / 4, 256, 0, stream>>>(
        y, row_ptr, sorted_src, normb, b_in, nullptr, nullptr, xc_x);

    // 6 residual blocks
    for (int i = 0; i < 6; ++i) {
        gemm_kernel<128><<<NPAD / 128, 256, 0, stream>>>(
            xc_x, wT + (size_t)(1 + i) * 32768, normb, y);
        gather_fin128<0, false><<<NNODES / 4, 256, 0, stream>>>(
            y, row_ptr, sorted_src, normb, b1 + i * HDIM, nullptr, nullptr, xc_h);
        gemm_kernel<128><<<NPAD / 128, 256, 0, stream>>>(
            xc_h, wT + (size_t)(7 + i) * 32768, normb, y);
        if (i < 5)
            gather_fin128<1, false><<<NNODES / 4, 256, 0, stream>>>(
                y, row_ptr, sorted_src, normb, b2 + i * HDIM, xc_x, nullptr, xc_x);
        else
            gather_fin128<1, true><<<NNODES / 4, 256, 0, stream>>>(
                y, row_ptr, sorted_src, normb, b2 + i * HDIM, xc_x, x, xc_x);
    }

    // output layer (H -> 64, identity)
    gemm_kernel<64><<<NPAD / 128, 256, 0, stream>>>(
        xc_x, wT + (size_t)13 * 32768, normb, y);
    gather_fin64<<<NNODES / 4, 256, 0, stream>>>(
        y, row_ptr, sorted_src, normb, b_out, xout);
}

// Round 7
// 1025.340 us; speedup vs baseline: 18.5239x; 1.0013x over previous
//
#include <hip/hip_runtime.h>

#define NNODES 50000
#define NPAD   50048   // 391 * 128
#define NEDGES 800000
#define HDIM 128
#define OUTDIM 64
#define NB 1563        // dst>>5 buckets (32 nodes each)
#define BCAP 1024      // slots per bucket (mean ~512, max ~620)

typedef short short8 __attribute__((ext_vector_type(8)));
typedef _Float16 half8 __attribute__((ext_vector_type(8)));
typedef float f32x4 __attribute__((ext_vector_type(4)));
typedef _Float16 f16x2 __attribute__((ext_vector_type(2)));

__device__ __forceinline__ unsigned short f2bf(float f) {
    unsigned int u = __builtin_bit_cast(unsigned int, f);
    unsigned int r = (u + 0x7FFFu + ((u >> 16) & 1u)) >> 16;
    return (unsigned short)r;
}
__device__ __forceinline__ float bf2f(unsigned short b) {
    unsigned int u = ((unsigned int)b) << 16;
    return __builtin_bit_cast(float, u);
}

// ---------------- CSR build: pass A (count + bucket scatter) ----------------
__global__ void passA_kernel(const int* __restrict__ src, const int* __restrict__ dst,
                             int* __restrict__ deg, int* __restrict__ bcnt,
                             unsigned* __restrict__ bkt) {
    int e = blockIdx.x * 256 + threadIdx.x;
    if (e < NEDGES) {
        int d = dst[e], s = src[e];
        atomicAdd(&deg[d], 1);
        int b = d >> 5;
        int pos = atomicAdd(&bcnt[b], 1);
        if (pos < BCAP) bkt[(size_t)b * BCAP + pos] = ((unsigned)s << 5) | (unsigned)(d & 31);
    }
}

__global__ __launch_bounds__(256) void bsum_kernel(const int* __restrict__ deg,
                                                   int* __restrict__ bsum) {
    __shared__ int red[256];
    int i = blockIdx.x * 256 + threadIdx.x;
    red[threadIdx.x] = (i < NNODES) ? deg[i] : 0;
    __syncthreads();
    for (int off = 128; off; off >>= 1) {
        if (threadIdx.x < off) red[threadIdx.x] += red[threadIdx.x + off];
        __syncthreads();
    }
    if (threadIdx.x == 0) bsum[blockIdx.x] = red[0];
}

__global__ __launch_bounds__(256) void bscan_kernel(const int* __restrict__ bsum,
                                                    int* __restrict__ bofs) {
    __shared__ int s[256];
    int t = threadIdx.x;
    int v = (t < 196) ? bsum[t] : 0;
    s[t] = v;
    __syncthreads();
    for (int off = 1; off < 256; off <<= 1) {
        int u = (t >= off) ? s[t - off] : 0;
        __syncthreads();
        s[t] += u;
        __syncthreads();
    }
    if (t < 196) bofs[t] = s[t] - v;  // exclusive
}

__global__ __launch_bounds__(256) void emit_kernel(
    const int* __restrict__ deg, const int* __restrict__ bofs,
    int* __restrict__ row_ptr, float* __restrict__ norm) {
    __shared__ int s[256];
    int t = threadIdx.x;
    int i = blockIdx.x * 256 + t;
    int v = (i < NNODES) ? deg[i] : 0;
    s[t] = v;
    __syncthreads();
    for (int off = 1; off < 256; off <<= 1) {
        int u = (t >= off) ? s[t - off] : 0;
        __syncthreads();
        s[t] += u;
        __syncthreads();
    }
    int excl = s[t] - v + bofs[blockIdx.x];
    if (i < NNODES) {
        row_ptr[i] = excl;
        norm[i] = rsqrtf(1.0f + (float)v);
    }
    if (i == NNODES - 1) row_ptr[NNODES] = NEDGES;
}

// ---------------- CSR build: pass B (per-bucket counting sort) --------------
__global__ __launch_bounds__(256) void passB_kernel(
    const int* __restrict__ bcnt, const unsigned* __restrict__ bkt,
    const int* __restrict__ row_ptr, int* __restrict__ sorted_src) {
    const int b = blockIdx.x;
    int nb = bcnt[b];
    if (nb > BCAP) nb = BCAP;
    const int node0 = b << 5;
    __shared__ int cnt[32];
    __shared__ int base[32];
    __shared__ int lsrc[BCAP];
    const int t = threadIdx.x;
    if (t < 32) cnt[t] = 0;
    __syncthreads();
    for (int i = t; i < nb; i += 256) {
        unsigned p = bkt[(size_t)b * BCAP + i];
        atomicAdd(&cnt[p & 31], 1);
    }
    __syncthreads();
    if (t == 0) {
        int r = 0;
        for (int j = 0; j < 32; ++j) { base[j] = r; r += cnt[j]; }
    }
    __syncthreads();
    if (t < 32) cnt[t] = base[t];
    __syncthreads();
    for (int i = t; i < nb; i += 256) {
        unsigned p = bkt[(size_t)b * BCAP + i];
        int pos = atomicAdd(&cnt[p & 31], 1);
        lsrc[pos] = (int)(p >> 5);
    }
    __syncthreads();
    const int gbase = row_ptr[node0];
    for (int i = t; i < nb; i += 256) sorted_src[gbase + i] = lsrc[i];
}

// ---------------- weight prep ----------------
// bf16 hi/lo (wT): w_in slot 0, w1[m] slot 1+m, w_out slot 7 (64 rows).
// f16 single (w2f): w2[m] at m*16384, layout [n][128].
__global__ __launch_bounds__(256) void prep_w_kernel(
    const float* __restrict__ w_in, const float* __restrict__ w1,
    const float* __restrict__ w2, const float* __restrict__ w_out,
    unsigned short* __restrict__ wT, _Float16* __restrict__ w2f) {
    int idx = blockIdx.x * 256 + threadIdx.x;  // total 221184 = 864*256
    if (idx < 16384 + 98304) {
        const float* W;
        unsigned short* o;
        int e;
        if (idx < 16384) {
            W = w_in; o = wT; e = idx;
        } else {
            int j = idx - 16384; int m = j >> 14; e = j & 16383;
            W = w1 + ((size_t)m << 14); o = wT + (size_t)(1 + m) * 32768;
        }
        int k = e >> 7, n = e & 127;
        float v = W[e];
        unsigned short h = f2bf(v);
        o[(size_t)n * 256 + k] = h;
        o[(size_t)n * 256 + 128 + k] = f2bf(v - bf2f(h));
    } else if (idx < 16384 + 196608) {
        int j = idx - 16384 - 98304; int m = j >> 14; int e = j & 16383;
        int k = e >> 7, n = e & 127;
        w2f[(size_t)m * 16384 + n * 128 + k] = (_Float16)w2[((size_t)m << 14) + e];
    } else {
        int e = idx - 212992;  // w_out: 8192 elements
        int k = e >> 6, n = e & 63;
        float v = w_out[e];
        unsigned short h = f2bf(v);
        unsigned short* o = wT + (size_t)7 * 32768;
        o[(size_t)n * 256 + k] = h;
        o[(size_t)n * 256 + 128 + k] = f2bf(v - bf2f(h));
    }
}

// ---------------- x split (input layer only) ----------------
__global__ __launch_bounds__(256) void split_x_kernel(
    const float* __restrict__ x, unsigned short* __restrict__ xc) {
    int gid = blockIdx.x * 256 + threadIdx.x;
    int row = gid >> 6;
    int kk = (gid & 63) * 2;
    float2 v = {0.f, 0.f};
    if (row < NNODES) v = *(const float2*)(x + (size_t)row * 128 + kk);
    unsigned short h0 = f2bf(v.x), h1 = f2bf(v.y);
    unsigned short l0 = f2bf(v.x - bf2f(h0)), l1 = f2bf(v.y - bf2f(h1));
    *(unsigned int*)(xc + (size_t)row * 256 + kk) =
        (unsigned int)h0 | ((unsigned int)h1 << 16);
    *(unsigned int*)(xc + (size_t)row * 256 + 128 + kk) =
        (unsigned int)l0 | ((unsigned int)l1 << 16);
}

// ---------------- bf16 hi/lo MFMA GEMM: y16 = ((hi+lo)@W)*norm ----------------
template <int NCOLS>
__global__ __launch_bounds__(256) void gemm_bf_kernel(
    const unsigned short* __restrict__ xc, const unsigned short* __restrict__ wT,
    const float* __restrict__ norm, _Float16* __restrict__ y) {
    constexpr int MT = (NCOLS == 128) ? 4 : 2;
    __shared__ unsigned short Alds[128 * 32];
    __shared__ unsigned short B1lds[NCOLS * 32];
    __shared__ unsigned short B2lds[NCOLS * 32];
    const int t = threadIdx.x;
    const int wave = t >> 6, lane = t & 63, quad = lane >> 4, l16 = lane & 15;
    const int row0 = blockIdx.x * 128;
    const int wm = (NCOLS == 128) ? (wave >> 1) * 64 : wave * 32;
    const int wn = (NCOLS == 128) ? (wave & 1) * 64 : 0;

    f32x4 acc[MT][4];
#pragma unroll
    for (int mt = 0; mt < MT; ++mt)
#pragma unroll
        for (int nt = 0; nt < 4; ++nt) acc[mt][nt] = (f32x4){0.f, 0.f, 0.f, 0.f};

    for (int ks = 0; ks < 8; ++ks) {
        const int k0 = ks * 32;
        const int kb = (ks < 4) ? k0 : (k0 - 128);
        __syncthreads();
#pragma unroll
        for (int i = 0; i < 2; ++i) {
            int c = i * 256 + t;
            int m = c >> 2, q = c & 3;
            const unsigned short* gp = xc + (size_t)(row0 + m) * 256 + k0 + q * 8;
            unsigned short* lp = Alds + (size_t)c * 8;
            __builtin_amdgcn_global_load_lds(
                (const __attribute__((address_space(1))) void*)gp,
                (__attribute__((address_space(3))) void*)lp, 16, 0, 0);
        }
#pragma unroll
        for (int i = 0; i < (NCOLS * 4) / 256; ++i) {
            int c = i * 256 + t;
            int n = c >> 2, q = c & 3;
            const unsigned short* gp = wT + (size_t)n * 256 + kb + q * 8;
            unsigned short* lp = B1lds + (size_t)c * 8;
            __builtin_amdgcn_global_load_lds(
                (const __attribute__((address_space(1))) void*)gp,
                (__attribute__((address_space(3))) void*)lp, 16, 0, 0);
        }
        if (ks < 4) {
#pragma unroll
            for (int i = 0; i < (NCOLS * 4) / 256; ++i) {
                int c = i * 256 + t;
                int n = c >> 2, q = c & 3;
                const unsigned short* gp = wT + (size_t)n * 256 + 128 + k0 + q * 8;
                unsigned short* lp = B2lds + (size_t)c * 8;
                __builtin_amdgcn_global_load_lds(
                    (const __attribute__((address_space(1))) void*)gp,
                    (__attribute__((address_space(3))) void*)lp, 16, 0, 0);
            }
        }
        __syncthreads();

        short8 a[MT], b1[4];
#pragma unroll
        for (int mt = 0; mt < MT; ++mt)
            a[mt] = *(const short8*)(Alds + (size_t)(wm + mt * 16 + l16) * 32 + quad * 8);
#pragma unroll
        for (int nt = 0; nt < 4; ++nt)
            b1[nt] = *(const short8*)(B1lds + (size_t)(wn + nt * 16 + l16) * 32 + quad * 8);
#pragma unroll
        for (int mt = 0; mt < MT; ++mt)
#pragma unroll
            for (int nt = 0; nt < 4; ++nt)
                acc[mt][nt] = __builtin_amdgcn_mfma_f32_16x16x32_bf16(
                    a[mt], b1[nt], acc[mt][nt], 0, 0, 0);
        if (ks < 4) {
            short8 b2[4];
#pragma unroll
            for (int nt = 0; nt < 4; ++nt)
                b2[nt] = *(const short8*)(B2lds + (size_t)(wn + nt * 16 + l16) * 32 + quad * 8);
#pragma unroll
            for (int mt = 0; mt < MT; ++mt)
#pragma unroll
                for (int nt = 0; nt < 4; ++nt)
                    acc[mt][nt] = __builtin_amdgcn_mfma_f32_16x16x32_bf16(
                        a[mt], b2[nt], acc[mt][nt], 0, 0, 0);
        }
    }

#pragma unroll
    for (int mt = 0; mt < MT; ++mt) {
        int mbase = row0 + wm + mt * 16 + quad * 4;
#pragma unroll
        for (int r = 0; r < 4; ++r) {
            int row = mbase + r;
            if (row < NNODES) {
                float nm = norm[row];
#pragma unroll
                for (int nt = 0; nt < 4; ++nt) {
                    int col = wn + nt * 16 + l16;
                    y[(size_t)row * NCOLS + col] = (_Float16)(acc[mt][nt][r] * nm);
                }
            }
        }
    }
}

// ---------------- f16 MFMA GEMM (x-conv): y16 = (h16 @ W2f)*norm -------------
__global__ __launch_bounds__(256) void gemm_f16_kernel(
    const _Float16* __restrict__ A, const _Float16* __restrict__ wf,
    const float* __restrict__ norm, _Float16* __restrict__ y) {
    __shared__ _Float16 Alds[128 * 32];
    __shared__ _Float16 Blds[128 * 32];
    const int t = threadIdx.x;
    const int wave = t >> 6, lane = t & 63, quad = lane >> 4, l16 = lane & 15;
    const int row0 = blockIdx.x * 128;
    const int wm = (wave >> 1) * 64;
    const int wn = (wave & 1) * 64;

    f32x4 acc[4][4];
#pragma unroll
    for (int mt = 0; mt < 4; ++mt)
#pragma unroll
        for (int nt = 0; nt < 4; ++nt) acc[mt][nt] = (f32x4){0.f, 0.f, 0.f, 0.f};

    for (int ks = 0; ks < 4; ++ks) {
        const int k0 = ks * 32;
        __syncthreads();
#pragma unroll
        for (int i = 0; i < 2; ++i) {
            int c = i * 256 + t;
            int m = c >> 2, q = c & 3;
            const _Float16* gp = A + (size_t)(row0 + m) * 128 + k0 + q * 8;
            _Float16* lp = Alds + (size_t)c * 8;
            __builtin_amdgcn_global_load_lds(
                (const __attribute__((address_space(1))) void*)gp,
                (__attribute__((address_space(3))) void*)lp, 16, 0, 0);
        }
#pragma unroll
        for (int i = 0; i < 2; ++i) {
            int c = i * 256 + t;
            int n = c >> 2, q = c & 3;
            const _Float16* gp = wf + (size_t)n * 128 + k0 + q * 8;
            _Float16* lp = Blds + (size_t)c * 8;
            __builtin_amdgcn_global_load_lds(
                (const __attribute__((address_space(1))) void*)gp,
                (__attribute__((address_space(3))) void*)lp, 16, 0, 0);
        }
        __syncthreads();

        half8 a[4], b[4];
#pragma unroll
        for (int mt = 0; mt < 4; ++mt)
            a[mt] = *(const half8*)(Alds + (size_t)(wm + mt * 16 + l16) * 32 + quad * 8);
#pragma unroll
        for (int nt = 0; nt < 4; ++nt)
            b[nt] = *(const half8*)(Blds + (size_t)(wn + nt * 16 + l16) * 32 + quad * 8);
#pragma unroll
        for (int mt = 0; mt < 4; ++mt)
#pragma unroll
            for (int nt = 0; nt < 4; ++nt)
                acc[mt][nt] = __builtin_amdgcn_mfma_f32_16x16x32_f16(
                    a[mt], b[nt], acc[mt][nt], 0, 0, 0);
    }

#pragma unroll
    for (int mt = 0; mt < 4; ++mt) {
        int mbase = row0 + wm + mt * 16 + quad * 4;
#pragma unroll
        for (int r = 0; r < 4; ++r) {
            int row = mbase + r;
            if (row < NNODES) {
                float nm = norm[row];
#pragma unroll
                for (int nt = 0; nt < 4; ++nt) {
                    int col = wn + nt * 16 + l16;
                    y[(size_t)row * 128 + col] = (_Float16)(acc[mt][nt][r] * nm);
                }
            }
        }
    }
}

// ---------------- fused gather + finalize (F=128, fp16 y) ----------------
// MODE 0: plain leaky; 1: residual from xcres (hi/lo bf16).
// OUT16: write h16 (f16 single); else write xcout (bf16 hi/lo).
// WOUT: also write fp32 out.
template <int MODE, bool WOUT, bool OUT16>
__global__ __launch_bounds__(256) void gather_fin128(
    const _Float16* __restrict__ y, const int* __restrict__ row_ptr,
    const int* __restrict__ sorted_src, const float* __restrict__ norm,
    const float* __restrict__ bias, const unsigned short* __restrict__ xcres,
    float* __restrict__ out, unsigned short* __restrict__ xcout,
    _Float16* __restrict__ h16) {
    const int wave = threadIdx.x >> 6;
    const int lane = threadIdx.x & 63;
    const int n = blockIdx.x * 4 + wave;
    const int beg = row_ptr[n];
    const int end = row_ptr[n + 1];

    float2 a0 = {0.f, 0.f}, a1 = a0, a2 = a0, a3 = a0, a4 = a0, a5 = a0, a6 = a0, a7 = a0;
    int i = beg;
    for (; i + 7 < end; i += 8) {
        int s0 = sorted_src[i], s1 = sorted_src[i + 1];
        int s2 = sorted_src[i + 2], s3 = sorted_src[i + 3];
        int s4 = sorted_src[i + 4], s5 = sorted_src[i + 5];
        int s6 = sorted_src[i + 6], s7 = sorted_src[i + 7];
        f16x2 h0 = *(const f16x2*)(y + (size_t)s0 * 128 + lane * 2);
        f16x2 h1 = *(const f16x2*)(y + (size_t)s1 * 128 + lane * 2);
        f16x2 h2 = *(const f16x2*)(y + (size_t)s2 * 128 + lane * 2);
        f16x2 h3 = *(const f16x2*)(y + (size_t)s3 * 128 + lane * 2);
        f16x2 h4 = *(const f16x2*)(y + (size_t)s4 * 128 + lane * 2);
        f16x2 h5 = *(const f16x2*)(y + (size_t)s5 * 128 + lane * 2);
        f16x2 h6 = *(const f16x2*)(y + (size_t)s6 * 128 + lane * 2);
        f16x2 h7 = *(const f16x2*)(y + (size_t)s7 * 128 + lane * 2);
        a0.x += (float)h0.x; a0.y += (float)h0.y;
        a1.x += (float)h1.x; a1.y += (float)h1.y;
        a2.x += (float)h2.x; a2.y += (float)h2.y;
        a3.x += (float)h3.x; a3.y += (float)h3.y;
        a4.x += (float)h4.x; a4.y += (float)h4.y;
        a5.x += (float)h5.x; a5.y += (float)h5.y;
        a6.x += (float)h6.x; a6.y += (float)h6.y;
        a7.x += (float)h7.x; a7.y += (float)h7.y;
    }
    for (; i < end; ++i) {
        int s = sorted_src[i];
        f16x2 h = *(const f16x2*)(y + (size_t)s * 128 + lane * 2);
        a0.x += (float)h.x; a0.y += (float)h.y;
    }
    a0.x += a1.x; a0.y += a1.y;
    a2.x += a3.x; a2.y += a3.y;
    a4.x += a5.x; a4.y += a5.y;
    a6.x += a7.x; a6.y += a7.y;
    a0.x += a2.x; a0.y += a2.y;
    a4.x += a6.x; a4.y += a6.y;
    a0.x += a4.x; a0.y += a4.y;

    const f16x2 sh = *(const f16x2*)(y + (size_t)n * 128 + lane * 2);
    const float2 bi = *(const float2*)(bias + lane * 2);
    const float nm = norm[n];
    float v0 = (a0.x + (float)sh.x) * nm + bi.x;
    float v1 = (a0.y + (float)sh.y) * nm + bi.y;
    v0 = v0 >= 0.f ? v0 : 0.01f * v0;
    v1 = v1 >= 0.f ? v1 : 0.01f * v1;
    if (MODE == 1) {
        unsigned int hw = *(const unsigned int*)(xcres + (size_t)n * 256 + lane * 2);
        unsigned int lw = *(const unsigned int*)(xcres + (size_t)n * 256 + 128 + lane * 2);
        float xr0 = bf2f((unsigned short)hw) + bf2f((unsigned short)lw);
        float xr1 = bf2f((unsigned short)(hw >> 16)) + bf2f((unsigned short)(lw >> 16));
        v0 = (xr0 + v0) * 0.5f;
        v1 = (xr1 + v1) * 0.5f;
    }
    if (WOUT) {
        float2 o = {v0, v1};
        *(float2*)(out + (size_t)n * 128 + lane * 2) = o;
    }
    if (OUT16) {
        f16x2 o16 = {(_Float16)v0, (_Float16)v1};
        *(f16x2*)(h16 + (size_t)n * 128 + lane * 2) = o16;
    } else {
        unsigned short h0 = f2bf(v0), h1 = f2bf(v1);
        unsigned short l0 = f2bf(v0 - bf2f(h0)), l1 = f2bf(v1 - bf2f(h1));
        *(unsigned int*)(xcout + (size_t)n * 256 + lane * 2) =
            (unsigned int)h0 | ((unsigned int)h1 << 16);
        *(unsigned int*)(xcout + (size_t)n * 256 + 128 + lane * 2) =
            (unsigned int)l0 | ((unsigned int)l1 << 16);
    }
}

// ---------------- final gather (F=64, identity, fp16 y) ----------------
__global__ __launch_bounds__(256) void gather_fin64(
    const _Float16* __restrict__ y, const int* __restrict__ row_ptr,
    const int* __restrict__ sorted_src, const float* __restrict__ norm,
    const float* __restrict__ bias, float* __restrict__ out) {
    const int wave = threadIdx.x >> 6;
    const int lane = threadIdx.x & 63;
    const int n = blockIdx.x * 4 + wave;
    const int beg = row_ptr[n];
    const int end = row_ptr[n + 1];
    float a0 = 0.f, a1 = 0.f, a2 = 0.f, a3 = 0.f;
    int i = beg;
    for (; i + 3 < end; i += 4) {
        int s0 = sorted_src[i], s1 = sorted_src[i + 1];
        int s2 = sorted_src[i + 2], s3 = sorted_src[i + 3];
        a0 += (float)y[(size_t)s0 * 64 + lane];
        a1 += (float)y[(size_t)s1 * 64 + lane];
        a2 += (float)y[(size_t)s2 * 64 + lane];
        a3 += (float)y[(size_t)s3 * 64 + lane];
    }
    for (; i < end; ++i) a0 += (float)y[(size_t)sorted_src[i] * 64 + lane];
    a0 += a1; a2 += a3; a0 += a2;
    float self = (float)y[(size_t)n * 64 + lane];
    out[(size_t)n * 64 + lane] = (a0 + self) * norm[n] + bias[lane];
}

extern "C" void kernel_launch(void* const* d_in, const int* in_sizes, int n_in,
                              void* d_out, int out_size, void* d_ws, size_t ws_size,
                              hipStream_t stream) {
    const float* inputs = (const float*)d_in[0];
    const int* edges = (const int*)d_in[1];
    const int* src = edges;
    const int* dst = edges + NEDGES;
    const float* w_in  = (const float*)d_in[2];
    const float* b_in  = (const float*)d_in[3];
    const float* w1    = (const float*)d_in[4];
    const float* b1    = (const float*)d_in[5];
    const float* w2    = (const float*)d_in[6];
    const float* b2    = (const float*)d_in[7];
    const float* w_out = (const float*)d_in[8];
    const float* b_out = (const float*)d_in[9];

    float* out  = (float*)d_out;
    float* xout = out;                                // [N, 64]
    float* x    = out + (size_t)NNODES * OUTDIM;      // [N, 128] fp32 x (final only)

    char* p = (char*)d_ws;
    auto alloc = [&](size_t bytes) {
        char* r = p;
        p += (bytes + 63) & ~(size_t)63;
        return r;
    };
    int* deg        = (int*)alloc((NNODES + NB) * 4);  // deg | bcnt contiguous
    int* bcnt       = deg + NNODES;
    int* row_ptr    = (int*)alloc((NNODES + 1) * 4);
    int* bsum       = (int*)alloc(256 * 4);
    int* bofs       = (int*)alloc(256 * 4);
    unsigned* bkt   = (unsigned*)alloc((size_t)NB * BCAP * 4);
    int* sorted_src = (int*)alloc(NEDGES * 4);
    float* normb    = (float*)alloc(NNODES * 4);
    unsigned short* wT = (unsigned short*)alloc((size_t)245760 * 2);  // 7*32768+16384
    _Float16* w2f   = (_Float16*)alloc((size_t)6 * 16384 * 2);
    unsigned short* xc_x = (unsigned short*)alloc((size_t)NPAD * 256 * 2);
    unsigned short* xc_in = (unsigned short*)alloc((size_t)NPAD * 256 * 2);
    _Float16* h16   = (_Float16*)alloc((size_t)NPAD * 128 * 2);
    _Float16* y     = (_Float16*)alloc((size_t)NNODES * HDIM * 2);

    // ---- CSR + norm + weight prep ----
    hipMemsetAsync(deg, 0, (NNODES + NB) * sizeof(int), stream);
    passA_kernel<<<(NEDGES + 255) / 256, 256, 0, stream>>>(src, dst, deg, bcnt, bkt);
    bsum_kernel<<<196, 256, 0, stream>>>(deg, bsum);
    bscan_kernel<<<1, 256, 0, stream>>>(bsum, bofs);
    emit_kernel<<<196, 256, 0, stream>>>(deg, bofs, row_ptr, normb);
    passB_kernel<<<NB, 256, 0, stream>>>(bcnt, bkt, row_ptr, sorted_src);
    prep_w_kernel<<<864, 256, 0, stream>>>(w_in, w1, w2, w_out, wT, w2f);

    // input layer
    split_x_kernel<<<(NPAD * 64) / 256, 256, 0, stream>>>(inputs, xc_in);
    gemm_bf_kernel<128><<<NPAD / 128, 256, 0, stream>>>(xc_in, wT, normb, y);
    gather_fin128<0, false, false><<<NNODES / 4, 256, 0, stream>>>(
        y, row_ptr, sorted_src, normb, b_in, nullptr, nullptr, xc_x, nullptr);

    // 6 residual blocks
    for (int i = 0; i < 6; ++i) {
        gemm_bf_kernel<128><<<NPAD / 128, 256, 0, stream>>>(
            xc_x, wT + (size_t)(1 + i) * 32768, normb, y);
        gather_fin128<0, false, true><<<NNODES / 4, 256, 0, stream>>>(
            y, row_ptr, sorted_src, normb, b1 + i * HDIM, nullptr, nullptr, nullptr, h16);
        gemm_f16_kernel<<<NPAD / 128, 256, 0, stream>>>(
            h16, w2f + (size_t)i * 16384, normb, y);
        if (i < 5)
            gather_fin128<1, false, false><<<NNODES / 4, 256, 0, stream>>>(
                y, row_ptr, sorted_src, normb, b2 + i * HDIM, xc_x, nullptr, xc_x, nullptr);
        else
            gather_fin128<1, true, false><<<NNODES / 4, 256, 0, stream>>>(
                y, row_ptr, sorted_src, normb, b2 + i * HDIM, xc_x, x, xc_x, nullptr);
    }

    // output layer (H -> 64, identity)
    gemm_bf_kernel<64><<<NPAD / 128, 256, 0, stream>>>(
        xc_x, wT + (size_t)7 * 32768, normb, y);
    gather_fin64<<<NNODES / 4, 256, 0, stream>>>(
        y, row_ptr, sorted_src, normb, b_out, xout);
}

// Round 8
// 919.470 us; speedup vs baseline: 20.6568x; 1.1151x over previous
//
#include <hip/hip_runtime.h>

#define NNODES 50000
#define NPAD   50048   // 391 * 128
#define NEDGES 800000
#define HDIM 128
#define OUTDIM 64

typedef short short8 __attribute__((ext_vector_type(8)));
typedef _Float16 half8 __attribute__((ext_vector_type(8)));
typedef float f32x4 __attribute__((ext_vector_type(4)));
typedef _Float16 f16x2 __attribute__((ext_vector_type(2)));

__device__ __forceinline__ unsigned short f2bf(float f) {
    unsigned int u = __builtin_bit_cast(unsigned int, f);
    unsigned int r = (u + 0x7FFFu + ((u >> 16) & 1u)) >> 16;
    return (unsigned short)r;
}
__device__ __forceinline__ float bf2f(unsigned short b) {
    unsigned int u = ((unsigned int)b) << 16;
    return __builtin_bit_cast(float, u);
}

// ---------------- CSR build ----------------
// count: deg histogram; epos[e] = this edge's slot within its dst's list.
__global__ void count_kernel(const int* __restrict__ dst, int* __restrict__ deg,
                             int* __restrict__ epos) {
    int e = blockIdx.x * 256 + threadIdx.x;
    if (e < NEDGES) epos[e] = atomicAdd(&deg[dst[e]], 1);
}

__global__ __launch_bounds__(256) void bsum_kernel(const int* __restrict__ deg,
                                                   int* __restrict__ bsum) {
    __shared__ int red[256];
    int i = blockIdx.x * 256 + threadIdx.x;
    red[threadIdx.x] = (i < NNODES) ? deg[i] : 0;
    __syncthreads();
    for (int off = 128; off; off >>= 1) {
        if (threadIdx.x < off) red[threadIdx.x] += red[threadIdx.x + off];
        __syncthreads();
    }
    if (threadIdx.x == 0) bsum[blockIdx.x] = red[0];
}

__global__ __launch_bounds__(256) void bscan_kernel(const int* __restrict__ bsum,
                                                    int* __restrict__ bofs) {
    __shared__ int s[256];
    int t = threadIdx.x;
    int v = (t < 196) ? bsum[t] : 0;
    s[t] = v;
    __syncthreads();
    for (int off = 1; off < 256; off <<= 1) {
        int u = (t >= off) ? s[t - off] : 0;
        __syncthreads();
        s[t] += u;
        __syncthreads();
    }
    if (t < 196) bofs[t] = s[t] - v;  // exclusive
}

__global__ __launch_bounds__(256) void emit_kernel(
    const int* __restrict__ deg, const int* __restrict__ bofs,
    int* __restrict__ row_ptr, float* __restrict__ norm) {
    __shared__ int s[256];
    int t = threadIdx.x;
    int i = blockIdx.x * 256 + t;
    int v = (i < NNODES) ? deg[i] : 0;
    s[t] = v;
    __syncthreads();
    for (int off = 1; off < 256; off <<= 1) {
        int u = (t >= off) ? s[t - off] : 0;
        __syncthreads();
        s[t] += u;
        __syncthreads();
    }
    int excl = s[t] - v + bofs[blockIdx.x];
    if (i < NNODES) {
        row_ptr[i] = excl;
        norm[i] = rsqrtf(1.0f + (float)v);
    }
    if (i == NNODES - 1) row_ptr[NNODES] = NEDGES;
}

// fill: atomic-free placement using precomputed epos.
__global__ void fill_kernel(const int* __restrict__ src, const int* __restrict__ dst,
                            const int* __restrict__ epos, const int* __restrict__ row_ptr,
                            int* __restrict__ sorted_src) {
    int e = blockIdx.x * 256 + threadIdx.x;
    if (e < NEDGES) sorted_src[row_ptr[dst[e]] + epos[e]] = src[e];
}

// ---------------- weight prep ----------------
// bf16 hi/lo (wT): w_in slot 0, w1[m] slot 1+m, w_out slot 7 (64 rows).
// f16 single (w2f): w2[m] at m*16384, layout [n][128].
__global__ __launch_bounds__(256) void prep_w_kernel(
    const float* __restrict__ w_in, const float* __restrict__ w1,
    const float* __restrict__ w2, const float* __restrict__ w_out,
    unsigned short* __restrict__ wT, _Float16* __restrict__ w2f) {
    int idx = blockIdx.x * 256 + threadIdx.x;  // total 221184 = 864*256
    if (idx < 16384 + 98304) {
        const float* W;
        unsigned short* o;
        int e;
        if (idx < 16384) {
            W = w_in; o = wT; e = idx;
        } else {
            int j = idx - 16384; int m = j >> 14; e = j & 16383;
            W = w1 + ((size_t)m << 14); o = wT + (size_t)(1 + m) * 32768;
        }
        int k = e >> 7, n = e & 127;
        float v = W[e];
        unsigned short h = f2bf(v);
        o[(size_t)n * 256 + k] = h;
        o[(size_t)n * 256 + 128 + k] = f2bf(v - bf2f(h));
    } else if (idx < 16384 + 196608) {
        int j = idx - 16384 - 98304; int m = j >> 14; int e = j & 16383;
        int k = e >> 7, n = e & 127;
        w2f[(size_t)m * 16384 + n * 128 + k] = (_Float16)w2[((size_t)m << 14) + e];
    } else {
        int e = idx - 212992;  // w_out: 8192 elements
        int k = e >> 6, n = e & 63;
        float v = w_out[e];
        unsigned short h = f2bf(v);
        unsigned short* o = wT + (size_t)7 * 32768;
        o[(size_t)n * 256 + k] = h;
        o[(size_t)n * 256 + 128 + k] = f2bf(v - bf2f(h));
    }
}

// ---------------- x split (input layer only) ----------------
__global__ __launch_bounds__(256) void split_x_kernel(
    const float* __restrict__ x, unsigned short* __restrict__ xc) {
    int gid = blockIdx.x * 256 + threadIdx.x;
    int row = gid >> 6;
    int kk = (gid & 63) * 2;
    float2 v = {0.f, 0.f};
    if (row < NNODES) v = *(const float2*)(x + (size_t)row * 128 + kk);
    unsigned short h0 = f2bf(v.x), h1 = f2bf(v.y);
    unsigned short l0 = f2bf(v.x - bf2f(h0)), l1 = f2bf(v.y - bf2f(h1));
    *(unsigned int*)(xc + (size_t)row * 256 + kk) =
        (unsigned int)h0 | ((unsigned int)h1 << 16);
    *(unsigned int*)(xc + (size_t)row * 256 + 128 + kk) =
        (unsigned int)l0 | ((unsigned int)l1 << 16);
}

// ---------------- bf16 hi/lo MFMA GEMM: y16 = ((hi+lo)@W)*norm ----------------
template <int NCOLS>
__global__ __launch_bounds__(256) void gemm_bf_kernel(
    const unsigned short* __restrict__ xc, const unsigned short* __restrict__ wT,
    const float* __restrict__ norm, _Float16* __restrict__ y) {
    constexpr int MT = (NCOLS == 128) ? 4 : 2;
    __shared__ unsigned short Alds[128 * 32];
    __shared__ unsigned short B1lds[NCOLS * 32];
    __shared__ unsigned short B2lds[NCOLS * 32];
    const int t = threadIdx.x;
    const int wave = t >> 6, lane = t & 63, quad = lane >> 4, l16 = lane & 15;
    const int row0 = blockIdx.x * 128;
    const int wm = (NCOLS == 128) ? (wave >> 1) * 64 : wave * 32;
    const int wn = (NCOLS == 128) ? (wave & 1) * 64 : 0;

    f32x4 acc[MT][4];
#pragma unroll
    for (int mt = 0; mt < MT; ++mt)
#pragma unroll
        for (int nt = 0; nt < 4; ++nt) acc[mt][nt] = (f32x4){0.f, 0.f, 0.f, 0.f};

    for (int ks = 0; ks < 8; ++ks) {
        const int k0 = ks * 32;
        const int kb = (ks < 4) ? k0 : (k0 - 128);
        __syncthreads();
#pragma unroll
        for (int i = 0; i < 2; ++i) {
            int c = i * 256 + t;
            int m = c >> 2, q = c & 3;
            const unsigned short* gp = xc + (size_t)(row0 + m) * 256 + k0 + q * 8;
            unsigned short* lp = Alds + (size_t)c * 8;
            __builtin_amdgcn_global_load_lds(
                (const __attribute__((address_space(1))) void*)gp,
                (__attribute__((address_space(3))) void*)lp, 16, 0, 0);
        }
#pragma unroll
        for (int i = 0; i < (NCOLS * 4) / 256; ++i) {
            int c = i * 256 + t;
            int n = c >> 2, q = c & 3;
            const unsigned short* gp = wT + (size_t)n * 256 + kb + q * 8;
            unsigned short* lp = B1lds + (size_t)c * 8;
            __builtin_amdgcn_global_load_lds(
                (const __attribute__((address_space(1))) void*)gp,
                (__attribute__((address_space(3))) void*)lp, 16, 0, 0);
        }
        if (ks < 4) {
#pragma unroll
            for (int i = 0; i < (NCOLS * 4) / 256; ++i) {
                int c = i * 256 + t;
                int n = c >> 2, q = c & 3;
                const unsigned short* gp = wT + (size_t)n * 256 + 128 + k0 + q * 8;
                unsigned short* lp = B2lds + (size_t)c * 8;
                __builtin_amdgcn_global_load_lds(
                    (const __attribute__((address_space(1))) void*)gp,
                    (__attribute__((address_space(3))) void*)lp, 16, 0, 0);
            }
        }
        __syncthreads();

        short8 a[MT], b1[4];
#pragma unroll
        for (int mt = 0; mt < MT; ++mt)
            a[mt] = *(const short8*)(Alds + (size_t)(wm + mt * 16 + l16) * 32 + quad * 8);
#pragma unroll
        for (int nt = 0; nt < 4; ++nt)
            b1[nt] = *(const short8*)(B1lds + (size_t)(wn + nt * 16 + l16) * 32 + quad * 8);
#pragma unroll
        for (int mt = 0; mt < MT; ++mt)
#pragma unroll
            for (int nt = 0; nt < 4; ++nt)
                acc[mt][nt] = __builtin_amdgcn_mfma_f32_16x16x32_bf16(
                    a[mt], b1[nt], acc[mt][nt], 0, 0, 0);
        if (ks < 4) {
            short8 b2[4];
#pragma unroll
            for (int nt = 0; nt < 4; ++nt)
                b2[nt] = *(const short8*)(B2lds + (size_t)(wn + nt * 16 + l16) * 32 + quad * 8);
#pragma unroll
            for (int mt = 0; mt < 4; ++mt)
#pragma unroll
                for (int nt = 0; nt < 4; ++nt)
                    acc[mt][nt] = __builtin_amdgcn_mfma_f32_16x16x32_bf16(
                        a[mt], b2[nt], acc[mt][nt], 0, 0, 0);
        }
    }

#pragma unroll
    for (int mt = 0; mt < MT; ++mt) {
        int mbase = row0 + wm + mt * 16 + quad * 4;
#pragma unroll
        for (int r = 0; r < 4; ++r) {
            int row = mbase + r;
            if (row < NNODES) {
                float nm = norm[row];
#pragma unroll
                for (int nt = 0; nt < 4; ++nt) {
                    int col = wn + nt * 16 + l16;
                    y[(size_t)row * NCOLS + col] = (_Float16)(acc[mt][nt][r] * nm);
                }
            }
        }
    }
}

// ---------------- f16 MFMA GEMM (x-conv): y16 = (h16 @ W2f)*norm -------------
__global__ __launch_bounds__(256) void gemm_f16_kernel(
    const _Float16* __restrict__ A, const _Float16* __restrict__ wf,
    const float* __restrict__ norm, _Float16* __restrict__ y) {
    __shared__ _Float16 Alds[128 * 32];
    __shared__ _Float16 Blds[128 * 32];
    const int t = threadIdx.x;
    const int wave = t >> 6, lane = t & 63, quad = lane >> 4, l16 = lane & 15;
    const int row0 = blockIdx.x * 128;
    const int wm = (wave >> 1) * 64;
    const int wn = (wave & 1) * 64;

    f32x4 acc[4][4];
#pragma unroll
    for (int mt = 0; mt < 4; ++mt)
#pragma unroll
        for (int nt = 0; nt < 4; ++nt) acc[mt][nt] = (f32x4){0.f, 0.f, 0.f, 0.f};

    for (int ks = 0; ks < 4; ++ks) {
        const int k0 = ks * 32;
        __syncthreads();
#pragma unroll
        for (int i = 0; i < 2; ++i) {
            int c = i * 256 + t;
            int m = c >> 2, q = c & 3;
            const _Float16* gp = A + (size_t)(row0 + m) * 128 + k0 + q * 8;
            _Float16* lp = Alds + (size_t)c * 8;
            __builtin_amdgcn_global_load_lds(
                (const __attribute__((address_space(1))) void*)gp,
                (__attribute__((address_space(3))) void*)lp, 16, 0, 0);
        }
#pragma unroll
        for (int i = 0; i < 2; ++i) {
            int c = i * 256 + t;
            int n = c >> 2, q = c & 3;
            const _Float16* gp = wf + (size_t)n * 128 + k0 + q * 8;
            _Float16* lp = Blds + (size_t)c * 8;
            __builtin_amdgcn_global_load_lds(
                (const __attribute__((address_space(1))) void*)gp,
                (__attribute__((address_space(3))) void*)lp, 16, 0, 0);
        }
        __syncthreads();

        half8 a[4], b[4];
#pragma unroll
        for (int mt = 0; mt < 4; ++mt)
            a[mt] = *(const half8*)(Alds + (size_t)(wm + mt * 16 + l16) * 32 + quad * 8);
#pragma unroll
        for (int nt = 0; nt < 4; ++nt)
            b[nt] = *(const half8*)(Blds + (size_t)(wn + nt * 16 + l16) * 32 + quad * 8);
#pragma unroll
        for (int mt = 0; mt < 4; ++mt)
#pragma unroll
            for (int nt = 0; nt < 4; ++nt)
                acc[mt][nt] = __builtin_amdgcn_mfma_f32_16x16x32_f16(
                    a[mt], b[nt], acc[mt][nt], 0, 0, 0);
    }

#pragma unroll
    for (int mt = 0; mt < 4; ++mt) {
        int mbase = row0 + wm + mt * 16 + quad * 4;
#pragma unroll
        for (int r = 0; r < 4; ++r) {
            int row = mbase + r;
            if (row < NNODES) {
                float nm = norm[row];
#pragma unroll
                for (int nt = 0; nt < 4; ++nt) {
                    int col = wn + nt * 16 + l16;
                    y[(size_t)row * 128 + col] = (_Float16)(acc[mt][nt][r] * nm);
                }
            }
        }
    }
}

// ---------------- fused gather + finalize (F=128, fp16 y) ----------------
// MODE 0: plain leaky; 1: residual from xcres (hi/lo bf16).
// OUT16: write h16 (f16 single); else write xcout (bf16 hi/lo).
// WOUT: also write fp32 out.
template <int MODE, bool WOUT, bool OUT16>
__global__ __launch_bounds__(256) void gather_fin128(
    const _Float16* __restrict__ y, const int* __restrict__ row_ptr,
    const int* __restrict__ sorted_src, const float* __restrict__ norm,
    const float* __restrict__ bias, const unsigned short* __restrict__ xcres,
    float* __restrict__ out, unsigned short* __restrict__ xcout,
    _Float16* __restrict__ h16) {
    const int wave = threadIdx.x >> 6;
    const int lane = threadIdx.x & 63;
    const int n = blockIdx.x * 4 + wave;
    const int beg = row_ptr[n];
    const int end = row_ptr[n + 1];

    float2 a0 = {0.f, 0.f}, a1 = a0, a2 = a0, a3 = a0, a4 = a0, a5 = a0, a6 = a0, a7 = a0;
    int i = beg;
    for (; i + 7 < end; i += 8) {
        int s0 = sorted_src[i], s1 = sorted_src[i + 1];
        int s2 = sorted_src[i + 2], s3 = sorted_src[i + 3];
        int s4 = sorted_src[i + 4], s5 = sorted_src[i + 5];
        int s6 = sorted_src[i + 6], s7 = sorted_src[i + 7];
        f16x2 h0 = *(const f16x2*)(y + (size_t)s0 * 128 + lane * 2);
        f16x2 h1 = *(const f16x2*)(y + (size_t)s1 * 128 + lane * 2);
        f16x2 h2 = *(const f16x2*)(y + (size_t)s2 * 128 + lane * 2);
        f16x2 h3 = *(const f16x2*)(y + (size_t)s3 * 128 + lane * 2);
        f16x2 h4 = *(const f16x2*)(y + (size_t)s4 * 128 + lane * 2);
        f16x2 h5 = *(const f16x2*)(y + (size_t)s5 * 128 + lane * 2);
        f16x2 h6 = *(const f16x2*)(y + (size_t)s6 * 128 + lane * 2);
        f16x2 h7 = *(const f16x2*)(y + (size_t)s7 * 128 + lane * 2);
        a0.x += (float)h0.x; a0.y += (float)h0.y;
        a1.x += (float)h1.x; a1.y += (float)h1.y;
        a2.x += (float)h2.x; a2.y += (float)h2.y;
        a3.x += (float)h3.x; a3.y += (float)h3.y;
        a4.x += (float)h4.x; a4.y += (float)h4.y;
        a5.x += (float)h5.x; a5.y += (float)h5.y;
        a6.x += (float)h6.x; a6.y += (float)h6.y;
        a7.x += (float)h7.x; a7.y += (float)h7.y;
    }
    for (; i < end; ++i) {
        int s = sorted_src[i];
        f16x2 h = *(const f16x2*)(y + (size_t)s * 128 + lane * 2);
        a0.x += (float)h.x; a0.y += (float)h.y;
    }
    a0.x += a1.x; a0.y += a1.y;
    a2.x += a3.x; a2.y += a3.y;
    a4.x += a5.x; a4.y += a5.y;
    a6.x += a7.x; a6.y += a7.y;
    a0.x += a2.x; a0.y += a2.y;
    a4.x += a6.x; a4.y += a6.y;
    a0.x += a4.x; a0.y += a4.y;

    const f16x2 sh = *(const f16x2*)(y + (size_t)n * 128 + lane * 2);
    const float2 bi = *(const float2*)(bias + lane * 2);
    const float nm = norm[n];
    float v0 = (a0.x + (float)sh.x) * nm + bi.x;
    float v1 = (a0.y + (float)sh.y) * nm + bi.y;
    v0 = v0 >= 0.f ? v0 : 0.01f * v0;
    v1 = v1 >= 0.f ? v1 : 0.01f * v1;
    if (MODE == 1) {
        unsigned int hw = *(const unsigned int*)(xcres + (size_t)n * 256 + lane * 2);
        unsigned int lw = *(const unsigned int*)(xcres + (size_t)n * 256 + 128 + lane * 2);
        float xr0 = bf2f((unsigned short)hw) + bf2f((unsigned short)lw);
        float xr1 = bf2f((unsigned short)(hw >> 16)) + bf2f((unsigned short)(lw >> 16));
        v0 = (xr0 + v0) * 0.5f;
        v1 = (xr1 + v1) * 0.5f;
    }
    if (WOUT) {
        float2 o = {v0, v1};
        *(float2*)(out + (size_t)n * 128 + lane * 2) = o;
    }
    if (OUT16) {
        f16x2 o16 = {(_Float16)v0, (_Float16)v1};
        *(f16x2*)(h16 + (size_t)n * 128 + lane * 2) = o16;
    } else {
        unsigned short h0 = f2bf(v0), h1 = f2bf(v1);
        unsigned short l0 = f2bf(v0 - bf2f(h0)), l1 = f2bf(v1 - bf2f(h1));
        *(unsigned int*)(xcout + (size_t)n * 256 + lane * 2) =
            (unsigned int)h0 | ((unsigned int)h1 << 16);
        *(unsigned int*)(xcout + (size_t)n * 256 + 128 + lane * 2) =
            (unsigned int)l0 | ((unsigned int)l1 << 16);
    }
}

// ---------------- final gather (F=64, identity, fp16 y) ----------------
__global__ __launch_bounds__(256) void gather_fin64(
    const _Float16* __restrict__ y, const int* __restrict__ row_ptr,
    const int* __restrict__ sorted_src, const float* __restrict__ norm,
    const float* __restrict__ bias, float* __restrict__ out) {
    const int wave = threadIdx.x >> 6;
    const int lane = threadIdx.x & 63;
    const int n = blockIdx.x * 4 + wave;
    const int beg = row_ptr[n];
    const int end = row_ptr[n + 1];
    float a0 = 0.f, a1 = 0.f, a2 = 0.f, a3 = 0.f;
    int i = beg;
    for (; i + 3 < end; i += 4) {
        int s0 = sorted_src[i], s1 = sorted_src[i + 1];
        int s2 = sorted_src[i + 2], s3 = sorted_src[i + 3];
        a0 += (float)y[(size_t)s0 * 64 + lane];
        a1 += (float)y[(size_t)s1 * 64 + lane];
        a2 += (float)y[(size_t)s2 * 64 + lane];
        a3 += (float)y[(size_t)s3 * 64 + lane];
    }
    for (; i < end; ++i) a0 += (float)y[(size_t)sorted_src[i] * 64 + lane];
    a0 += a1; a2 += a3; a0 += a2;
    float self = (float)y[(size_t)n * 64 + lane];
    out[(size_t)n * 64 + lane] = (a0 + self) * norm[n] + bias[lane];
}

extern "C" void kernel_launch(void* const* d_in, const int* in_sizes, int n_in,
                              void* d_out, int out_size, void* d_ws, size_t ws_size,
                              hipStream_t stream) {
    const float* inputs = (const float*)d_in[0];
    const int* edges = (const int*)d_in[1];
    const int* src = edges;
    const int* dst = edges + NEDGES;
    const float* w_in  = (const float*)d_in[2];
    const float* b_in  = (const float*)d_in[3];
    const float* w1    = (const float*)d_in[4];
    const float* b1    = (const float*)d_in[5];
    const float* w2    = (const float*)d_in[6];
    const float* b2    = (const float*)d_in[7];
    const float* w_out = (const float*)d_in[8];
    const float* b_out = (const float*)d_in[9];

    float* out  = (float*)d_out;
    float* xout = out;                                // [N, 64]
    float* x    = out + (size_t)NNODES * OUTDIM;      // [N, 128] fp32 x (final only)

    char* p = (char*)d_ws;
    auto alloc = [&](size_t bytes) {
        char* r = p;
        p += (bytes + 63) & ~(size_t)63;
        return r;
    };
    int* deg        = (int*)alloc(NNODES * 4);
    int* epos       = (int*)alloc(NEDGES * 4);
    int* row_ptr    = (int*)alloc((NNODES + 1) * 4);
    int* bsum       = (int*)alloc(256 * 4);
    int* bofs       = (int*)alloc(256 * 4);
    int* sorted_src = (int*)alloc(NEDGES * 4);
    float* normb    = (float*)alloc(NNODES * 4);
    unsigned short* wT = (unsigned short*)alloc((size_t)245760 * 2);  // 7*32768+16384
    _Float16* w2f   = (_Float16*)alloc((size_t)6 * 16384 * 2);
    unsigned short* xc_x = (unsigned short*)alloc((size_t)NPAD * 256 * 2);
    unsigned short* xc_in = (unsigned short*)alloc((size_t)NPAD * 256 * 2);
    _Float16* h16   = (_Float16*)alloc((size_t)NPAD * 128 * 2);
    _Float16* y     = (_Float16*)alloc((size_t)NNODES * HDIM * 2);

    // ---- CSR + norm + weight prep ----
    hipMemsetAsync(deg, 0, NNODES * sizeof(int), stream);
    count_kernel<<<(NEDGES + 255) / 256, 256, 0, stream>>>(dst, deg, epos);
    bsum_kernel<<<196, 256, 0, stream>>>(deg, bsum);
    bscan_kernel<<<1, 256, 0, stream>>>(bsum, bofs);
    emit_kernel<<<196, 256, 0, stream>>>(deg, bofs, row_ptr, normb);
    fill_kernel<<<(NEDGES + 255) / 256, 256, 0, stream>>>(src, dst, epos, row_ptr, sorted_src);
    prep_w_kernel<<<864, 256, 0, stream>>>(w_in, w1, w2, w_out, wT, w2f);

    // input layer
    split_x_kernel<<<(NPAD * 64) / 256, 256, 0, stream>>>(inputs, xc_in);
    gemm_bf_kernel<128><<<NPAD / 128, 256, 0, stream>>>(xc_in, wT, normb, y);
    gather_fin128<0, false, false><<<NNODES / 4, 256, 0, stream>>>(
        y, row_ptr, sorted_src, normb, b_in, nullptr, nullptr, xc_x, nullptr);

    // 6 residual blocks
    for (int i = 0; i < 6; ++i) {
        gemm_bf_kernel<128><<<NPAD / 128, 256, 0, stream>>>(
            xc_x, wT + (size_t)(1 + i) * 32768, normb, y);
        gather_fin128<0, false, true><<<NNODES / 4, 256, 0, stream>>>(
            y, row_ptr, sorted_src, normb, b1 + i * HDIM, nullptr, nullptr, nullptr, h16);
        gemm_f16_kernel<<<NPAD / 128, 256, 0, stream>>>(
            h16, w2f + (size_t)i * 16384, normb, y);
        if (i < 5)
            gather_fin128<1, false, false><<<NNODES / 4, 256, 0, stream>>>(
                y, row_ptr, sorted_src, normb, b2 + i * HDIM, xc_x, nullptr, xc_x, nullptr);
        else
            gather_fin128<1, true, false><<<NNODES / 4, 256, 0, stream>>>(
                y, row_ptr, sorted_src, normb, b2 + i * HDIM, xc_x, x, xc_x, nullptr);
    }

    // output layer (H -> 64, identity)
    gemm_bf_kernel<64><<<NPAD / 128, 256, 0, stream>>>(
        xc_x, wT + (size_t)7 * 32768, normb, y);
    gather_fin64<<<NNODES / 4, 256, 0, stream>>>(
        y, row_ptr, sorted_src, normb, b_out, xout);
}